// Round 1
// baseline (1787.634 us; speedup 1.0000x reference)
//
#include <hip/hip_runtime.h>
#include <hip/hip_bf16.h>

// ---------------- constants ----------------
static constexpr int B_   = 8;
static constexpr int LQ_  = 1800;
static constexpr int D_   = 256;
static constexpr int H_   = 8;
static constexpr int DH_  = 32;
static constexpr int DFF_ = 1024;
static constexpr int LIN_ = 19947;          // 15000 + 3750 + 950 + 247
static constexpr int MQ_  = B_ * LQ_;       // 14400
static constexpr int NELEM_ = MQ_ * D_;     // 3,686,400

#define CDIV(a, b) (((a) + (b) - 1) / (b))

// ---------------- dtype helper ----------------
template <typename T> __device__ __forceinline__ T cvt_store(float v);
template <> __device__ __forceinline__ float cvt_store<float>(float v) { return v; }
template <> __device__ __forceinline__ __hip_bfloat16 cvt_store<__hip_bfloat16>(float v) {
    return __float2bfloat16(v);
}

// ---------------- LSQ weight quantization (forward) ----------------
// lsq(w, alpha) forward == rint(clip(w/alpha, -8, 7)) * alpha   (rint = RNE = jnp.round)
__global__ void k_quant(const float* __restrict__ w, const float* __restrict__ alpha,
                        float* __restrict__ o, int n) {
    int i = blockIdx.x * blockDim.x + threadIdx.x;
    if (i >= n) return;
    float a = alpha[0];
    float wn = w[i] / a;
    wn = fminf(fmaxf(wn, -8.f), 7.f);
    o[i] = rintf(wn) * a;
}

// ---------------- elementwise add ----------------
__global__ void k_add(const float* __restrict__ a, const float* __restrict__ b,
                      float* __restrict__ o, int n) {
    int i = blockIdx.x * blockDim.x + threadIdx.x;
    if (i < n) o[i] = a[i] + b[i];
}

// ---------------- GEMM: Y = X @ W^T + bias, optional relu ----------------
// X: (M,K) row-major, W: (N,K) row-major, Y: (M,N).
// 64x64 tile, 256 threads (16x16), 4x4 acc per thread, BK=16 staged in LDS.
template <typename OT, bool RELU>
__global__ __launch_bounds__(256) void k_gemm(
    const float* __restrict__ X, const float* __restrict__ W,
    const float* __restrict__ bias, OT* __restrict__ Y,
    int M, int N, int K)
{
    __shared__ float Xs[64][17];   // +1 pad: kills stride-16 bank conflicts
    __shared__ float Ws[64][17];
    const int tid = threadIdx.x;
    const int tx = tid & 15, ty = tid >> 4;
    const int bm = blockIdx.x << 6, bn = blockIdx.y << 6;
    const int lr = tid >> 2;            // 0..63 load row
    const int lc = (tid & 3) << 2;      // 0,4,8,12 load col
    float acc[4][4] = {};

    for (int k0 = 0; k0 < K; k0 += 16) {
        float4 xv = make_float4(0.f, 0.f, 0.f, 0.f);
        int xr = bm + lr;
        if (xr < M) xv = *reinterpret_cast<const float4*>(&X[(size_t)xr * K + k0 + lc]);
        Xs[lr][lc + 0] = xv.x; Xs[lr][lc + 1] = xv.y;
        Xs[lr][lc + 2] = xv.z; Xs[lr][lc + 3] = xv.w;
        // N is always a multiple of 64 here (128/256/1024) -> no bounds check
        float4 wv = *reinterpret_cast<const float4*>(&W[(size_t)(bn + lr) * K + k0 + lc]);
        Ws[lr][lc + 0] = wv.x; Ws[lr][lc + 1] = wv.y;
        Ws[lr][lc + 2] = wv.z; Ws[lr][lc + 3] = wv.w;
        __syncthreads();
        #pragma unroll
        for (int kk = 0; kk < 16; ++kk) {
            float a_[4], b_[4];
            a_[0] = Xs[ty +  0][kk]; a_[1] = Xs[ty + 16][kk];
            a_[2] = Xs[ty + 32][kk]; a_[3] = Xs[ty + 48][kk];
            b_[0] = Ws[tx +  0][kk]; b_[1] = Ws[tx + 16][kk];
            b_[2] = Ws[tx + 32][kk]; b_[3] = Ws[tx + 48][kk];
            #pragma unroll
            for (int i = 0; i < 4; ++i)
                #pragma unroll
                for (int j = 0; j < 4; ++j)
                    acc[i][j] += a_[i] * b_[j];
        }
        __syncthreads();
    }
    #pragma unroll
    for (int i = 0; i < 4; ++i) {
        int m = bm + ty + 16 * i;
        if (m >= M) continue;
        #pragma unroll
        for (int j = 0; j < 4; ++j) {
            int n = bn + tx + 16 * j;
            float v = acc[i][j] + bias[n];
            if (RELU) v = fmaxf(v, 0.f);
            Y[(size_t)m * N + n] = cvt_store<OT>(v);
        }
    }
}

// ---------------- flash self-attention (f32) ----------------
// Q,K,V,O: (B, LQ, D) with head h occupying columns [h*32, h*32+32).
// Block = 256 threads handles 64 query rows for one (b,h); 4 threads per row
// split the key space (k % 4); online softmax; shfl combine at the end.
__global__ __launch_bounds__(256) void k_attn(
    const float* __restrict__ Q, const float* __restrict__ K,
    const float* __restrict__ V, float* __restrict__ O)
{
    __shared__ float Ks[64][36];   // row stride 36 floats: 16B-aligned rows, banks spread
    __shared__ float Vs[64][36];
    const int b = blockIdx.z, h = blockIdx.y;
    const int q0 = blockIdx.x << 6;
    const int tid = threadIdx.x;
    const int qr = tid >> 2;        // local query row 0..63
    const int kc = tid & 3;         // key partition 0..3
    const int qg = q0 + qr;
    const float scale = 0.17677669529663687f;   // 1/sqrt(32)

    float qreg[32];
    if (qg < LQ_) {
        const float* qp = Q + ((size_t)(b * LQ_ + qg)) * D_ + h * DH_;
        #pragma unroll
        for (int d = 0; d < 32; d += 4) {
            float4 t = *reinterpret_cast<const float4*>(qp + d);
            qreg[d] = t.x; qreg[d + 1] = t.y; qreg[d + 2] = t.z; qreg[d + 3] = t.w;
        }
    } else {
        #pragma unroll
        for (int d = 0; d < 32; ++d) qreg[d] = 0.f;
    }

    float m = -1e30f, l = 0.f;
    float acc[32];
    #pragma unroll
    for (int d = 0; d < 32; ++d) acc[d] = 0.f;

    for (int kb0 = 0; kb0 < LQ_; kb0 += 64) {
        __syncthreads();
        #pragma unroll
        for (int s = 0; s < 2; ++s) {
            int slot = tid + (s << 8);          // 0..511 float4 slots
            int row = slot >> 3;
            int col = (slot & 7) << 2;
            int kg = kb0 + row;
            float4 kv = make_float4(0.f, 0.f, 0.f, 0.f);
            float4 vv = make_float4(0.f, 0.f, 0.f, 0.f);
            if (kg < LQ_) {
                size_t base = ((size_t)(b * LQ_ + kg)) * D_ + h * DH_ + col;
                kv = *reinterpret_cast<const float4*>(K + base);
                vv = *reinterpret_cast<const float4*>(V + base);
            }
            *reinterpret_cast<float4*>(&Ks[row][col]) = kv;
            *reinterpret_cast<float4*>(&Vs[row][col]) = vv;
        }
        __syncthreads();

        float sreg[16];
        float mnew = m;
        #pragma unroll
        for (int j = 0; j < 16; ++j) {
            int kk = kc + (j << 2);
            float dot = 0.f;
            #pragma unroll
            for (int d = 0; d < 32; ++d) dot += qreg[d] * Ks[kk][d];
            sreg[j] = (kb0 + kk < LQ_) ? dot * scale : -1e30f;
            mnew = fmaxf(mnew, sreg[j]);
        }
        float rescale = expf(m - mnew);
        m = mnew;
        l *= rescale;
        #pragma unroll
        for (int d = 0; d < 32; ++d) acc[d] *= rescale;
        #pragma unroll
        for (int j = 0; j < 16; ++j) {
            int kk = kc + (j << 2);
            float p = expf(sreg[j] - m);
            l += p;
            #pragma unroll
            for (int d = 0; d < 32; ++d) acc[d] += p * Vs[kk][d];
        }
    }

    // combine the 4 key-partitions of each row (lanes kc=0..3 are adjacent)
    float m1 = fmaxf(m, __shfl_xor(m, 1));
    float M2 = fmaxf(m1, __shfl_xor(m1, 2));
    float p = expf(m - M2);
    float lp = l * p;
    lp += __shfl_xor(lp, 1);
    lp += __shfl_xor(lp, 2);
    #pragma unroll
    for (int d = 0; d < 32; ++d) {
        float a = acc[d] * p;
        a += __shfl_xor(a, 1);
        a += __shfl_xor(a, 2);
        acc[d] = a;
    }
    if (kc == 0 && qg < LQ_) {
        float inv = 1.f / lp;
        float* op = O + ((size_t)(b * LQ_ + qg)) * D_ + h * DH_;
        #pragma unroll
        for (int d = 0; d < 32; d += 4) {
            float4 t = make_float4(acc[d] * inv, acc[d + 1] * inv,
                                   acc[d + 2] * inv, acc[d + 3] * inv);
            *reinterpret_cast<float4*>(op + d) = t;
        }
    }
}

// ---------------- residual + LayerNorm: O = LN(R + X)*g + b ----------------
__global__ __launch_bounds__(256) void k_resln(
    const float* __restrict__ X, const float* __restrict__ R,
    const float* __restrict__ g, const float* __restrict__ bb,
    float* __restrict__ O)
{
    const int row = blockIdx.x;
    const int d = threadIdx.x;
    const size_t off = (size_t)row * D_ + d;
    float v = R[off] + X[off];
    __shared__ float r1[4], r2[4];
    int lane = d & 63, wid = d >> 6;
    float s = v;
    #pragma unroll
    for (int o_ = 32; o_ >= 1; o_ >>= 1) s += __shfl_xor(s, o_);
    if (lane == 0) r1[wid] = s;
    __syncthreads();
    float mean = (r1[0] + r1[1] + r1[2] + r1[3]) * (1.f / 256.f);
    float dv = v - mean;
    float sq = dv * dv;
    #pragma unroll
    for (int o_ = 32; o_ >= 1; o_ >>= 1) sq += __shfl_xor(sq, o_);
    if (lane == 0) r2[wid] = sq;
    __syncthreads();
    float var = (r2[0] + r2[1] + r2[2] + r2[3]) * (1.f / 256.f);
    O[off] = dv / sqrtf(var + 1e-5f) * g[d] + bb[d];
}

// ---------------- attention-weight softmax over 16 (per b,q,h) ----------------
__global__ void k_awsm(float* __restrict__ aw) {
    int i = blockIdx.x * blockDim.x + threadIdx.x;
    if (i >= MQ_ * H_) return;
    float* p = aw + (size_t)i * 16;   // (b*LQ+q)*128 + h*16 == i*16
    float mx = p[0];
    #pragma unroll
    for (int j = 1; j < 16; ++j) mx = fmaxf(mx, p[j]);
    float e[16], s = 0.f;
    #pragma unroll
    for (int j = 0; j < 16; ++j) { e[j] = expf(p[j] - mx); s += e[j]; }
    float inv = 1.f / s;
    #pragma unroll
    for (int j = 0; j < 16; ++j) p[j] = e[j] * inv;
}

// ---------------- deformable sampling ----------------
// 1 thread per (b,q,h,dh). offs: (B,LQ,256) layout h*32+l*8+p*2+c.
// aw (post-softmax): (B,LQ,128) layout h*16+l*4+p. value: bf16 (B,LIN,H,DH).
__global__ __launch_bounds__(256) void k_sample(
    const float* __restrict__ offs, const float* __restrict__ aw,
    const __hip_bfloat16* __restrict__ value, const float* __restrict__ refp,
    float* __restrict__ acc_out)
{
    int idx = blockIdx.x * 256 + threadIdx.x;
    if (idx >= NELEM_) return;
    const int dh = idx & 31;
    const int h = (idx >> 5) & 7;
    const int bq = idx >> 8;                    // b*LQ + q
    const float* op = offs + (size_t)bq * 256 + h * 32;
    const float* ap = aw + (size_t)bq * 128 + h * 16;
    const float* rp = refp + (size_t)bq * 8;    // (B,LQ,NL,2)
    const __hip_bfloat16* vb = value + (size_t)(bq / LQ_) * LIN_ * 256 + h * 32 + dh;

    constexpr int Hl[4] = {100, 50, 25, 13};
    constexpr int Wl[4] = {150, 75, 38, 19};
    constexpr int LS[4] = {0, 15000, 18750, 19700};

    float acc = 0.f;
    #pragma unroll
    for (int l = 0; l < 4; ++l) {
        const float rx = rp[l * 2 + 0], ry = rp[l * 2 + 1];
        const float Wf = (float)Wl[l], Hf = (float)Hl[l];
        #pragma unroll
        for (int p_ = 0; p_ < 4; ++p_) {
            float ox = op[l * 8 + p_ * 2 + 0];
            float oy = op[l * 8 + p_ * 2 + 1];
            // replicate reference expression order exactly
            float locx = rx + ox / Wf;
            float locy = ry + oy / Hf;
            float x = locx * Wf - 0.5f;
            float y = locy * Hf - 0.5f;
            float x0f = floorf(x), y0f = floorf(y);
            int x0 = (int)x0f, y0 = (int)y0f;
            float wx1 = x - x0f, wy1 = y - y0f;
            float wx0 = 1.f - wx1, wy0 = 1.f - wy1;
            float a = ap[l * 4 + p_];
            float samp = 0.f;
            #pragma unroll
            for (int cy = 0; cy < 2; ++cy) {
                #pragma unroll
                for (int cx = 0; cx < 2; ++cx) {
                    int yi = y0 + cy, xi = x0 + cx;
                    if (yi >= 0 && yi < Hl[l] && xi >= 0 && xi < Wl[l]) {
                        float gv = __bfloat162float(
                            vb[(size_t)(LS[l] + yi * Wl[l] + xi) * 256]);
                        samp += gv * (cy ? wy1 : wy0) * (cx ? wx1 : wx0);
                    }
                }
            }
            acc += a * samp;
        }
    }
    acc_out[idx] = acc;   // (B,LQ,H,DH) flat == idx
}

// ---------------- launch ----------------
extern "C" void kernel_launch(void* const* d_in, const int* in_sizes, int n_in,
                              void* d_out, int out_size, void* d_ws, size_t ws_size,
                              hipStream_t stream)
{
    (void)in_sizes; (void)n_in; (void)out_size; (void)ws_size;
    const float* tgt   = (const float*)d_in[0];
    const float* qpos  = (const float*)d_in[1];
    const float* refp  = (const float*)d_in[2];
    const float* src   = (const float*)d_in[3];
    const float* qW    = (const float*)d_in[4];
    const float* qb    = (const float*)d_in[5];
    const float* kW    = (const float*)d_in[6];
    const float* kb    = (const float*)d_in[7];
    const float* vW    = (const float*)d_in[8];
    const float* vb    = (const float*)d_in[9];
    const float* oW    = (const float*)d_in[10];
    const float* ob    = (const float*)d_in[11];
    const float* a_q   = (const float*)d_in[12];
    const float* a_k   = (const float*)d_in[13];
    const float* a_v   = (const float*)d_in[14];
    const float* a_o   = (const float*)d_in[15];
    const float* val_W = (const float*)d_in[16];
    const float* val_b = (const float*)d_in[17];
    const float* a_val = (const float*)d_in[18];
    const float* off_W = (const float*)d_in[19];
    const float* off_b = (const float*)d_in[20];
    const float* aw_W  = (const float*)d_in[21];
    const float* aw_b  = (const float*)d_in[22];
    const float* out_W = (const float*)d_in[23];
    const float* out_b = (const float*)d_in[24];
    const float* a_out = (const float*)d_in[25];
    const float* W1    = (const float*)d_in[26];
    const float* b1    = (const float*)d_in[27];
    const float* a_w1  = (const float*)d_in[28];
    const float* W2    = (const float*)d_in[29];
    const float* b2    = (const float*)d_in[30];
    const float* a_w2  = (const float*)d_in[31];
    const float* ln1_g = (const float*)d_in[32];
    const float* ln1_b = (const float*)d_in[33];
    const float* ln2_g = (const float*)d_in[34];
    const float* ln2_b = (const float*)d_in[35];
    const float* ln3_g = (const float*)d_in[36];
    const float* ln3_b = (const float*)d_in[37];

    // ---- workspace layout (floats) ----
    float* ws = (float*)d_ws;
    float* WQq   = ws;                  // 65536
    float* WQk   = WQq   + 65536;
    float* WQv   = WQk   + 65536;
    float* WQo   = WQv   + 65536;
    float* WQval = WQo   + 65536;
    float* WQout = WQval + 65536;
    float* WQ1   = WQout + 65536;       // 262144
    float* WQ2   = WQ1   + 262144;      // 262144
    float* buf0  = WQ2   + 262144;      // 3,686,400 each
    float* buf1  = buf0  + NELEM_;
    float* buf2  = buf1  + NELEM_;
    float* buf3  = buf2  + NELEM_;
    __hip_bfloat16* valb = (__hip_bfloat16*)(buf3 + NELEM_);  // B*LIN*256 bf16
    float* ffn1 = buf3 + NELEM_;        // reuses value region (value dead by then)

    const int TB = 256;
    // ---- quantize weights ----
    k_quant<<<256, TB, 0, stream>>>(qW, a_q, WQq, 65536);
    k_quant<<<256, TB, 0, stream>>>(kW, a_k, WQk, 65536);
    k_quant<<<256, TB, 0, stream>>>(vW, a_v, WQv, 65536);
    k_quant<<<256, TB, 0, stream>>>(oW, a_o, WQo, 65536);
    k_quant<<<256, TB, 0, stream>>>(val_W, a_val, WQval, 65536);
    k_quant<<<256, TB, 0, stream>>>(out_W, a_out, WQout, 65536);
    k_quant<<<1024, TB, 0, stream>>>(W1, a_w1, WQ1, 262144);
    k_quant<<<1024, TB, 0, stream>>>(W2, a_w2, WQ2, 262144);

    dim3 g256(CDIV(MQ_, 64), 4);     // N=256
    dim3 g128(CDIV(MQ_, 64), 2);     // N=128
    dim3 g1024(CDIV(MQ_, 64), 16);   // N=1024
    dim3 gval(CDIV(B_ * LIN_, 64), 4);

    // ---- self-attention ----
    k_add<<<CDIV(NELEM_, TB), TB, 0, stream>>>(tgt, qpos, buf0, NELEM_);      // qk_in
    k_gemm<float, false><<<g256, TB, 0, stream>>>(buf0, WQq, qb, buf1, MQ_, 256, 256);  // q
    k_gemm<float, false><<<g256, TB, 0, stream>>>(buf0, WQk, kb, buf2, MQ_, 256, 256);  // k
    k_gemm<float, false><<<g256, TB, 0, stream>>>(tgt,  WQv, vb, buf3, MQ_, 256, 256);  // v
    k_attn<<<dim3(CDIV(LQ_, 64), H_, B_), TB, 0, stream>>>(buf1, buf2, buf3, buf0);     // sa
    k_gemm<float, false><<<g256, TB, 0, stream>>>(buf0, WQo, ob, buf1, MQ_, 256, 256);  // o
    k_resln<<<MQ_, TB, 0, stream>>>(buf1, tgt, ln2_g, ln2_b, buf2);                     // tgt2

    // ---- deformable cross-attention ----
    k_add<<<CDIV(NELEM_, TB), TB, 0, stream>>>(buf2, qpos, buf0, NELEM_);     // query
    k_gemm<__hip_bfloat16, false><<<gval, TB, 0, stream>>>(src, WQval, val_b, valb,
                                                           B_ * LIN_, 256, 256);  // value
    k_gemm<float, false><<<g256, TB, 0, stream>>>(buf0, off_W, off_b, buf1, MQ_, 256, 256); // offs
    k_gemm<float, false><<<g128, TB, 0, stream>>>(buf0, aw_W, aw_b, buf3, MQ_, 128, 256);   // aw
    k_awsm<<<CDIV(MQ_ * H_, TB), TB, 0, stream>>>(buf3);
    k_sample<<<CDIV(NELEM_, TB), TB, 0, stream>>>(buf1, buf3, valb, refp, buf0);        // acc
    k_gemm<float, false><<<g256, TB, 0, stream>>>(buf0, WQout, out_b, buf1, MQ_, 256, 256); // ca
    k_resln<<<MQ_, TB, 0, stream>>>(buf1, buf2, ln1_g, ln1_b, buf3);                    // tgt3

    // ---- FFN ----
    k_gemm<float, true ><<<g1024, TB, 0, stream>>>(buf3, WQ1, b1, ffn1, MQ_, 1024, 256);
    k_gemm<float, false><<<g256,  TB, 0, stream>>>(ffn1, WQ2, b2, buf0, MQ_, 256, 1024);
    k_resln<<<MQ_, TB, 0, stream>>>(buf0, buf3, ln3_g, ln3_b, (float*)d_out);
}

// Round 2
// 619.959 us; speedup vs baseline: 2.8835x; 2.8835x over previous
//
#include <hip/hip_runtime.h>
#include <hip/hip_bf16.h>

// ---------------- constants ----------------
static constexpr int B_   = 8;
static constexpr int LQ_  = 1800;
static constexpr int D_   = 256;
static constexpr int H_   = 8;
static constexpr int DFF_ = 1024;
static constexpr int LIN_ = 19947;
static constexpr int MQ_  = B_ * LQ_;       // 14400
static constexpr int NELEM_ = MQ_ * D_;     // 3,686,400
static constexpr float SCALE_ = 0.17677669529663687f;  // 1/sqrt(32)

#define CDIV(a, b) (((a) + (b) - 1) / (b))

typedef unsigned short u16;
typedef unsigned int   u32;
typedef __attribute__((ext_vector_type(8))) __bf16 bf16x8;
typedef __attribute__((ext_vector_type(4))) float  f32x4;

// ---------------- bf16 helpers (RNE) ----------------
__device__ __forceinline__ u16 f2bf(float f) {
    union { float f; u32 u; } v; v.f = f;
    u32 r = v.u + 0x7fffu + ((v.u >> 16) & 1u);
    return (u16)(r >> 16);
}
__device__ __forceinline__ float bf2f(u16 u) {
    union { u32 u; float f; } v; v.u = ((u32)u) << 16;
    return v.f;
}

__device__ __forceinline__ f32x4 mfma_bf16(bf16x8 a, bf16x8 b, f32x4 c) {
    return __builtin_amdgcn_mfma_f32_16x16x32_bf16(a, b, c, 0, 0, 0);
}

// ---------------- small elementwise kernels ----------------
__global__ void k_quant(const float* __restrict__ w, const float* __restrict__ alpha,
                        u16* __restrict__ o, int n) {
    int i = blockIdx.x * blockDim.x + threadIdx.x;
    if (i >= n) return;
    float a = alpha[0];
    float wn = fminf(fmaxf(w[i] / a, -8.f), 7.f);
    o[i] = f2bf(rintf(wn) * a);
}

__global__ void k_cvt(const float* __restrict__ w, u16* __restrict__ o, int n) {
    int i = blockIdx.x * blockDim.x + threadIdx.x;
    if (i < n) o[i] = f2bf(w[i]);
}

__global__ void k_addcvt(const float* __restrict__ a, const float* __restrict__ b,
                         u16* __restrict__ o, int n) {
    int i = blockIdx.x * blockDim.x + threadIdx.x;
    if (i < n) o[i] = f2bf(a[i] + b[i]);
}

__global__ void k_addcvt2(const u16* __restrict__ a, const float* __restrict__ b,
                          u16* __restrict__ o, int n) {
    int i = blockIdx.x * blockDim.x + threadIdx.x;
    if (i < n) o[i] = f2bf(bf2f(a[i]) + b[i]);
}

// ---------------- GEMM: Y = X @ W^T + bias (MFMA bf16) ----------------
__device__ __forceinline__ bf16x8 loadx(const u16* p) { return *(const bf16x8*)p; }
__device__ __forceinline__ bf16x8 loadx(const float* p) {
    float4 a = *(const float4*)p;
    float4 b = *(const float4*)(p + 4);
    union { bf16x8 v; u16 s[8]; } r;
    r.s[0] = f2bf(a.x); r.s[1] = f2bf(a.y); r.s[2] = f2bf(a.z); r.s[3] = f2bf(a.w);
    r.s[4] = f2bf(b.x); r.s[5] = f2bf(b.y); r.s[6] = f2bf(b.z); r.s[7] = f2bf(b.w);
    return r.v;
}
__device__ __forceinline__ void storey(float* p, float v) { *p = v; }
__device__ __forceinline__ void storey(u16* p, float v)   { *p = f2bf(v); }

// 128x128 tile, BK=32, 256 threads = 4 waves (2x2), each wave 64x64 (4x4 frags).
template <typename XT, typename OT, bool RELU>
__global__ __launch_bounds__(256) void k_gemm(
    const XT* __restrict__ X, const u16* __restrict__ W,
    const float* __restrict__ bias, OT* __restrict__ Y,
    int M, int N, int K)
{
    __shared__ u16 As[128 * 40];   // 40-elem stride: 16B-aligned rows, banks spread
    __shared__ u16 Bs[128 * 40];
    const int tid = threadIdx.x;
    const int wave = tid >> 6, lane = tid & 63;
    const int wr = wave >> 1, wc = wave & 1;
    const int fr = lane & 15, fg = lane >> 4;
    const int bm = blockIdx.x * 128, bn = blockIdx.y * 128;
    const int srow = tid >> 2, sc = (tid & 3) * 8;

    f32x4 acc[4][4];
    #pragma unroll
    for (int m = 0; m < 4; ++m)
        #pragma unroll
        for (int n = 0; n < 4; ++n) acc[m][n] = (f32x4){0.f, 0.f, 0.f, 0.f};

    for (int k0 = 0; k0 < K; k0 += 32) {
        __syncthreads();
        #pragma unroll
        for (int i = 0; i < 2; ++i) {
            int row = srow + i * 64;
            int gr = bm + row; if (gr > M - 1) gr = M - 1;
            bf16x8 xa = loadx(X + (size_t)gr * K + k0 + sc);
            *(bf16x8*)&As[row * 40 + sc] = xa;
            bf16x8 wb = *(const bf16x8*)(W + (size_t)(bn + row) * K + k0 + sc);
            *(bf16x8*)&Bs[row * 40 + sc] = wb;
        }
        __syncthreads();
        bf16x8 af[4], bg[4];
        #pragma unroll
        for (int m = 0; m < 4; ++m)
            af[m] = *(const bf16x8*)&As[(wr * 64 + m * 16 + fr) * 40 + fg * 8];
        #pragma unroll
        for (int n = 0; n < 4; ++n)
            bg[n] = *(const bf16x8*)&Bs[(wc * 64 + n * 16 + fr) * 40 + fg * 8];
        #pragma unroll
        for (int m = 0; m < 4; ++m)
            #pragma unroll
            for (int n = 0; n < 4; ++n)
                acc[m][n] = mfma_bf16(af[m], bg[n], acc[m][n]);
    }

    #pragma unroll
    for (int m = 0; m < 4; ++m) {
        #pragma unroll
        for (int i = 0; i < 4; ++i) {
            int grow = bm + wr * 64 + m * 16 + fg * 4 + i;
            if (grow >= M) continue;
            #pragma unroll
            for (int n = 0; n < 4; ++n) {
                int gcol = bn + wc * 64 + n * 16 + fr;
                float v = acc[m][n][i] + bias[gcol];
                if (RELU) v = fmaxf(v, 0.f);
                storey(Y + (size_t)grow * N + gcol, v);
            }
        }
    }
}

// ---------------- flash self-attention (MFMA bf16) ----------------
// Q,K,V,O: (B,LQ,256) bf16, head h = cols [h*32, h*32+32).
// Block: 256 thr = 4 waves; block owns 64 queries, wave owns 16.
// S^T = K.Q^T (q = lane&15), softmax stats via shfl_xor(16/32),
// P -> per-wave LDS bf16, PV as O^T = V^T . P^T.
__global__ __launch_bounds__(256) void k_attn(
    const u16* __restrict__ Q, const u16* __restrict__ K,
    const u16* __restrict__ V, u16* __restrict__ O)
{
    __shared__ u16 Ks[64 * 40];       // [key][dh], stride 40
    __shared__ u16 Vt[32 * 72];       // [dh][kv],  stride 72
    __shared__ u16 Ps[4 * 16 * 72];   // per-wave [q][kv], stride 72
    const int b = blockIdx.z, h = blockIdx.y;
    const int q0 = blockIdx.x * 64;
    const int tid = threadIdx.x;
    const int wave = tid >> 6, lane = tid & 63;
    const int fr = lane & 15, fg = lane >> 4;
    u16* Pw = &Ps[wave * 16 * 72];

    int qg = q0 + wave * 16 + fr; if (qg >= LQ_) qg = LQ_ - 1;
    const bf16x8 qf = *(const bf16x8*)&Q[((size_t)(b * LQ_ + qg)) * 256 + h * 32 + fg * 8];

    f32x4 o0 = (f32x4){0.f,0.f,0.f,0.f}, o1 = (f32x4){0.f,0.f,0.f,0.f};
    float m_run = -1e30f, l_run = 0.f;

    const int key_t = tid >> 2, kc8 = (tid & 3) * 8;   // K staging
    const int vkv = tid & 63, vdh = (tid >> 6) * 8;    // V staging (transpose)

    for (int kb0 = 0; kb0 < LQ_; kb0 += 64) {
        __syncthreads();
        {
            int kg = kb0 + key_t; if (kg >= LQ_) kg = LQ_ - 1;
            bf16x8 kv = *(const bf16x8*)&K[((size_t)(b * LQ_ + kg)) * 256 + h * 32 + kc8];
            *(bf16x8*)&Ks[key_t * 40 + kc8] = kv;
            int vg = kb0 + vkv; if (vg >= LQ_) vg = LQ_ - 1;
            union { bf16x8 v; u16 s[8]; } vv;
            vv.v = *(const bf16x8*)&V[((size_t)(b * LQ_ + vg)) * 256 + h * 32 + vdh];
            #pragma unroll
            for (int j = 0; j < 8; ++j) Vt[(vdh + j) * 72 + vkv] = vv.s[j];
        }
        __syncthreads();

        // S^T fragments: key = kb0 + f*16 + fg*4 + i, q = fr
        f32x4 st[4];
        #pragma unroll
        for (int f = 0; f < 4; ++f) {
            bf16x8 ka = *(const bf16x8*)&Ks[(f * 16 + fr) * 40 + fg * 8];
            st[f] = mfma_bf16(ka, qf, (f32x4){0.f,0.f,0.f,0.f});
        }

        float mx = -1e30f;
        #pragma unroll
        for (int f = 0; f < 4; ++f) {
            #pragma unroll
            for (int i = 0; i < 4; ++i) {
                int key = kb0 + f * 16 + fg * 4 + i;
                float s = st[f][i] * SCALE_;
                s = (key < LQ_) ? s : -1e30f;
                st[f][i] = s;
                mx = fmaxf(mx, s);
            }
        }
        mx = fmaxf(mx, __shfl_xor(mx, 16));
        mx = fmaxf(mx, __shfl_xor(mx, 32));
        float mnew = fmaxf(m_run, mx);
        float fac = __expf(m_run - mnew);

        float psum = 0.f;
        u32 pw[8];
        #pragma unroll
        for (int f = 0; f < 4; ++f) {
            float p0 = __expf(st[f][0] - mnew), p1 = __expf(st[f][1] - mnew);
            float p2 = __expf(st[f][2] - mnew), p3 = __expf(st[f][3] - mnew);
            psum += (p0 + p1) + (p2 + p3);
            pw[f * 2 + 0] = (u32)f2bf(p0) | ((u32)f2bf(p1) << 16);
            pw[f * 2 + 1] = (u32)f2bf(p2) | ((u32)f2bf(p3) << 16);
        }
        psum += __shfl_xor(psum, 16);
        psum += __shfl_xor(psum, 32);
        l_run = l_run * fac + psum;
        m_run = mnew;
        #pragma unroll
        for (int i = 0; i < 4; ++i) { o0[i] *= fac; o1[i] *= fac; }

        // write P (bf16, packed pairs): P[q=fr][kv = f*16 + fg*4 + {0..3}]
        #pragma unroll
        for (int f = 0; f < 4; ++f) {
            *(u32*)&Pw[fr * 72 + f * 16 + fg * 4]     = pw[f * 2 + 0];
            *(u32*)&Pw[fr * 72 + f * 16 + fg * 4 + 2] = pw[f * 2 + 1];
        }
        asm volatile("s_waitcnt lgkmcnt(0)" ::: "memory");  // drain P writes (same-wave RAW)

        // PV: O^T(dh,q) += V^T(dh,kv) . P^T(kv,q)
        #pragma unroll
        for (int ks = 0; ks < 2; ++ks) {
            bf16x8 pb  = *(const bf16x8*)&Pw[fr * 72 + ks * 32 + fg * 8];
            bf16x8 va0 = *(const bf16x8*)&Vt[fr * 72 + ks * 32 + fg * 8];
            bf16x8 va1 = *(const bf16x8*)&Vt[(16 + fr) * 72 + ks * 32 + fg * 8];
            o0 = mfma_bf16(va0, pb, o0);
            o1 = mfma_bf16(va1, pb, o1);
        }
    }

    float inv = 1.f / l_run;
    int qout = q0 + wave * 16 + fr;
    if (qout < LQ_) {
        size_t base = ((size_t)(b * LQ_ + qout)) * 256 + h * 32;
        #pragma unroll
        for (int i = 0; i < 4; ++i) {
            O[base + fg * 4 + i]      = f2bf(o0[i] * inv);
            O[base + 16 + fg * 4 + i] = f2bf(o1[i] * inv);
        }
    }
}

// ---------------- residual + LayerNorm ----------------
__device__ __forceinline__ float ldf(const float* p) { return *p; }
__device__ __forceinline__ float ldf(const u16* p)   { return bf2f(*p); }

template <typename RT, typename OT>
__global__ __launch_bounds__(256) void k_resln(
    const u16* __restrict__ X, const RT* __restrict__ R,
    const float* __restrict__ g, const float* __restrict__ bb,
    OT* __restrict__ O)
{
    const int row = blockIdx.x;
    const int d = threadIdx.x;
    const size_t off = (size_t)row * D_ + d;
    float v = ldf(R + off) + bf2f(X[off]);
    __shared__ float r1[4], r2[4];
    int lane = d & 63, wid = d >> 6;
    float s = v;
    #pragma unroll
    for (int o_ = 32; o_ >= 1; o_ >>= 1) s += __shfl_xor(s, o_);
    if (lane == 0) r1[wid] = s;
    __syncthreads();
    float mean = (r1[0] + r1[1] + r1[2] + r1[3]) * (1.f / 256.f);
    float dv = v - mean;
    float sq = dv * dv;
    #pragma unroll
    for (int o_ = 32; o_ >= 1; o_ >>= 1) sq += __shfl_xor(sq, o_);
    if (lane == 0) r2[wid] = sq;
    __syncthreads();
    float var = (r2[0] + r2[1] + r2[2] + r2[3]) * (1.f / 256.f);
    storey(O + off, dv / sqrtf(var + 1e-5f) * g[d] + bb[d]);
}

// ---------------- attention-weight softmax over 16 ----------------
__global__ void k_awsm(float* __restrict__ aw) {
    int i = blockIdx.x * blockDim.x + threadIdx.x;
    if (i >= MQ_ * H_) return;
    float* p = aw + (size_t)i * 16;
    float mx = p[0];
    #pragma unroll
    for (int j = 1; j < 16; ++j) mx = fmaxf(mx, p[j]);
    float e[16], s = 0.f;
    #pragma unroll
    for (int j = 0; j < 16; ++j) { e[j] = __expf(p[j] - mx); s += e[j]; }
    float inv = 1.f / s;
    #pragma unroll
    for (int j = 0; j < 16; ++j) p[j] = e[j] * inv;
}

// ---------------- deformable sampling ----------------
__global__ __launch_bounds__(256) void k_sample(
    const float* __restrict__ offs, const float* __restrict__ aw,
    const u16* __restrict__ value, const float* __restrict__ refp,
    u16* __restrict__ acc_out)
{
    int idx = blockIdx.x * 256 + threadIdx.x;
    if (idx >= NELEM_) return;
    const int dh = idx & 31;
    const int h = (idx >> 5) & 7;
    const int bq = idx >> 8;
    const float* op = offs + (size_t)bq * 256 + h * 32;
    const float* ap = aw + (size_t)bq * 128 + h * 16;
    const float* rp = refp + (size_t)bq * 8;
    const u16* vb = value + (size_t)(bq / LQ_) * LIN_ * 256 + h * 32 + dh;

    constexpr int Hl[4] = {100, 50, 25, 13};
    constexpr int Wl[4] = {150, 75, 38, 19};
    constexpr int LS[4] = {0, 15000, 18750, 19700};

    float acc = 0.f;
    #pragma unroll
    for (int l = 0; l < 4; ++l) {
        const float rx = rp[l * 2 + 0], ry = rp[l * 2 + 1];
        const float Wf = (float)Wl[l], Hf = (float)Hl[l];
        #pragma unroll
        for (int p_ = 0; p_ < 4; ++p_) {
            float ox = op[l * 8 + p_ * 2 + 0];
            float oy = op[l * 8 + p_ * 2 + 1];
            float x = (rx + ox / Wf) * Wf - 0.5f;
            float y = (ry + oy / Hf) * Hf - 0.5f;
            float x0f = floorf(x), y0f = floorf(y);
            int x0 = (int)x0f, y0 = (int)y0f;
            float wx1 = x - x0f, wy1 = y - y0f;
            float wx0 = 1.f - wx1, wy0 = 1.f - wy1;
            float a = ap[l * 4 + p_];
            float samp = 0.f;
            #pragma unroll
            for (int cy = 0; cy < 2; ++cy)
                #pragma unroll
                for (int cx = 0; cx < 2; ++cx) {
                    int yi = y0 + cy, xi = x0 + cx;
                    if (yi >= 0 && yi < Hl[l] && xi >= 0 && xi < Wl[l]) {
                        float gv = bf2f(vb[(size_t)(LS[l] + yi * Wl[l] + xi) * 256]);
                        samp += gv * (cy ? wy1 : wy0) * (cx ? wx1 : wx0);
                    }
                }
            acc += a * samp;
        }
    }
    acc_out[idx] = f2bf(acc);
}

// ---------------- launch ----------------
extern "C" void kernel_launch(void* const* d_in, const int* in_sizes, int n_in,
                              void* d_out, int out_size, void* d_ws, size_t ws_size,
                              hipStream_t stream)
{
    (void)in_sizes; (void)n_in; (void)out_size; (void)ws_size;
    const float* tgt   = (const float*)d_in[0];
    const float* qpos  = (const float*)d_in[1];
    const float* refp  = (const float*)d_in[2];
    const float* src   = (const float*)d_in[3];
    const float* qW    = (const float*)d_in[4];
    const float* qb    = (const float*)d_in[5];
    const float* kW    = (const float*)d_in[6];
    const float* kb    = (const float*)d_in[7];
    const float* vW    = (const float*)d_in[8];
    const float* vb    = (const float*)d_in[9];
    const float* oW    = (const float*)d_in[10];
    const float* ob    = (const float*)d_in[11];
    const float* a_q   = (const float*)d_in[12];
    const float* a_k   = (const float*)d_in[13];
    const float* a_v   = (const float*)d_in[14];
    const float* a_o   = (const float*)d_in[15];
    const float* val_W = (const float*)d_in[16];
    const float* val_b = (const float*)d_in[17];
    const float* a_val = (const float*)d_in[18];
    const float* off_W = (const float*)d_in[19];
    const float* off_b = (const float*)d_in[20];
    const float* aw_W  = (const float*)d_in[21];
    const float* aw_b  = (const float*)d_in[22];
    const float* out_W = (const float*)d_in[23];
    const float* out_b = (const float*)d_in[24];
    const float* a_out = (const float*)d_in[25];
    const float* W1    = (const float*)d_in[26];
    const float* b1    = (const float*)d_in[27];
    const float* a_w1  = (const float*)d_in[28];
    const float* W2    = (const float*)d_in[29];
    const float* b2    = (const float*)d_in[30];
    const float* a_w2  = (const float*)d_in[31];
    const float* ln1_g = (const float*)d_in[32];
    const float* ln1_b = (const float*)d_in[33];
    const float* ln2_g = (const float*)d_in[34];
    const float* ln2_b = (const float*)d_in[35];
    const float* ln3_g = (const float*)d_in[36];
    const float* ln3_b = (const float*)d_in[37];

    // ---- workspace layout ----
    u16* wq_q  = (u16*)d_ws;
    u16* wq_k  = wq_q + 65536;
    u16* wq_v  = wq_k + 65536;
    u16* wq_o  = wq_v + 65536;
    u16* wq_vl = wq_o + 65536;
    u16* wq_ot = wq_vl + 65536;
    u16* w_off = wq_ot + 65536;
    u16* w_aw  = w_off + 65536;
    u16* wq_1  = w_aw + 32768;
    u16* wq_2  = wq_1 + 262144;
    u16* bufA  = wq_2 + 262144;      // NELEM bf16 each
    u16* bufB  = bufA + NELEM_;
    u16* bufC  = bufB + NELEM_;
    u16* bufD  = bufC + NELEM_;
    u16* bufE  = bufD + NELEM_;
    float* offs = (float*)(bufE + NELEM_);   // NELEM f32
    float* awb  = offs + NELEM_;             // MQ*128 f32
    u16* valb   = (u16*)(awb + MQ_ * 128);   // B*LIN*256 bf16 (later reused as ffn1)

    const int TB = 256;
    const int MVAL = B_ * LIN_;

    // weights
    k_quant<<<CDIV(65536, TB), TB, 0, stream>>>(qW, a_q, wq_q, 65536);
    k_quant<<<CDIV(65536, TB), TB, 0, stream>>>(kW, a_k, wq_k, 65536);
    k_quant<<<CDIV(65536, TB), TB, 0, stream>>>(vW, a_v, wq_v, 65536);
    k_quant<<<CDIV(65536, TB), TB, 0, stream>>>(oW, a_o, wq_o, 65536);
    k_quant<<<CDIV(65536, TB), TB, 0, stream>>>(val_W, a_val, wq_vl, 65536);
    k_quant<<<CDIV(65536, TB), TB, 0, stream>>>(out_W, a_out, wq_ot, 65536);
    k_quant<<<CDIV(262144, TB), TB, 0, stream>>>(W1, a_w1, wq_1, 262144);
    k_quant<<<CDIV(262144, TB), TB, 0, stream>>>(W2, a_w2, wq_2, 262144);
    k_cvt<<<CDIV(65536, TB), TB, 0, stream>>>(off_W, w_off, 65536);
    k_cvt<<<CDIV(32768, TB), TB, 0, stream>>>(aw_W, w_aw, 32768);

    // activation prep
    k_addcvt<<<CDIV(NELEM_, TB), TB, 0, stream>>>(tgt, qpos, bufA, NELEM_);  // qk_in
    k_cvt<<<CDIV(NELEM_, TB), TB, 0, stream>>>(tgt, bufB, NELEM_);           // tgt_bf

    // ---- self-attention ----
    k_gemm<u16, u16, false><<<dim3(CDIV(MQ_,128), 2), TB, 0, stream>>>(bufA, wq_q, qb, bufC, MQ_, 256, 256);
    k_gemm<u16, u16, false><<<dim3(CDIV(MQ_,128), 2), TB, 0, stream>>>(bufA, wq_k, kb, bufD, MQ_, 256, 256);
    k_gemm<u16, u16, false><<<dim3(CDIV(MQ_,128), 2), TB, 0, stream>>>(bufB, wq_v, vb, bufE, MQ_, 256, 256);
    k_attn<<<dim3(CDIV(LQ_,64), H_, B_), TB, 0, stream>>>(bufC, bufD, bufE, bufA);       // sa -> A
    k_gemm<u16, u16, false><<<dim3(CDIV(MQ_,128), 2), TB, 0, stream>>>(bufA, wq_o, ob, bufB, MQ_, 256, 256);
    k_resln<float, u16><<<MQ_, TB, 0, stream>>>(bufB, tgt, ln2_g, ln2_b, bufC);          // tgt2 -> C

    // ---- deformable cross-attention ----
    k_addcvt2<<<CDIV(NELEM_, TB), TB, 0, stream>>>(bufC, qpos, bufD, NELEM_);            // query -> D
    k_gemm<float, u16, false><<<dim3(CDIV(MVAL,128), 2), TB, 0, stream>>>(src, wq_vl, val_b, valb, MVAL, 256, 256);
    k_gemm<u16, float, false><<<dim3(CDIV(MQ_,128), 2), TB, 0, stream>>>(bufD, w_off, off_b, offs, MQ_, 256, 256);
    k_gemm<u16, float, false><<<dim3(CDIV(MQ_,128), 1), TB, 0, stream>>>(bufD, w_aw, aw_b, awb, MQ_, 128, 256);
    k_awsm<<<CDIV(MQ_ * H_, TB), TB, 0, stream>>>(awb);
    k_sample<<<CDIV(NELEM_, TB), TB, 0, stream>>>(offs, awb, valb, refp, bufE);          // acc -> E
    k_gemm<u16, u16, false><<<dim3(CDIV(MQ_,128), 2), TB, 0, stream>>>(bufE, wq_ot, out_b, bufA, MQ_, 256, 256);
    k_resln<u16, u16><<<MQ_, TB, 0, stream>>>(bufA, bufC, ln1_g, ln1_b, bufB);           // tgt3 -> B

    // ---- FFN ----
    u16* ffn1 = valb;  // value dead after k_sample
    k_gemm<u16, u16, true ><<<dim3(CDIV(MQ_,128), 8), TB, 0, stream>>>(bufB, wq_1, b1, ffn1, MQ_, 1024, 256);
    k_gemm<u16, u16, false><<<dim3(CDIV(MQ_,128), 2), TB, 0, stream>>>(ffn1, wq_2, b2, bufD, MQ_, 256, 1024);
    k_resln<u16, float><<<MQ_, TB, 0, stream>>>(bufD, bufB, ln3_g, ln3_b, (float*)d_out);
}

// Round 3
// 507.348 us; speedup vs baseline: 3.5235x; 1.2220x over previous
//
#include <hip/hip_runtime.h>
#include <hip/hip_bf16.h>

// ---------------- constants ----------------
static constexpr int B_   = 8;
static constexpr int LQ_  = 1800;
static constexpr int D_   = 256;
static constexpr int H_   = 8;
static constexpr int DFF_ = 1024;
static constexpr int LIN_ = 19947;
static constexpr int MQ_  = B_ * LQ_;       // 14400
static constexpr int NELEM_ = MQ_ * D_;     // 3,686,400
static constexpr float SCALE_ = 0.17677669529663687f;  // 1/sqrt(32)

#define CDIV(a, b) (((a) + (b) - 1) / (b))

typedef unsigned short u16;
typedef unsigned int   u32;
typedef __attribute__((ext_vector_type(8))) __bf16 bf16x8;
typedef __attribute__((ext_vector_type(4))) float  f32x4;

// ---------------- bf16 helpers (RNE) ----------------
__device__ __forceinline__ u16 f2bf(float f) {
    union { float f; u32 u; } v; v.f = f;
    u32 r = v.u + 0x7fffu + ((v.u >> 16) & 1u);
    return (u16)(r >> 16);
}
__device__ __forceinline__ float bf2f(u16 u) {
    union { u32 u; float f; } v; v.u = ((u32)u) << 16;
    return v.f;
}

__device__ __forceinline__ f32x4 mfma_bf16(bf16x8 a, bf16x8 b, f32x4 c) {
    return __builtin_amdgcn_mfma_f32_16x16x32_bf16(a, b, c, 0, 0, 0);
}

// ---------------- small elementwise kernels ----------------
__global__ void k_quant(const float* __restrict__ w, const float* __restrict__ alpha,
                        u16* __restrict__ o, int n) {
    int i = blockIdx.x * blockDim.x + threadIdx.x;
    if (i >= n) return;
    float a = alpha[0];
    float wn = fminf(fmaxf(w[i] / a, -8.f), 7.f);
    o[i] = f2bf(rintf(wn) * a);
}

__global__ void k_cvt(const float* __restrict__ w, u16* __restrict__ o, int n) {
    int i = blockIdx.x * blockDim.x + threadIdx.x;
    if (i < n) o[i] = f2bf(w[i]);
}

__global__ void k_addcvt(const float* __restrict__ a, const float* __restrict__ b,
                         u16* __restrict__ o, int n) {
    int i = blockIdx.x * blockDim.x + threadIdx.x;
    if (i < n) o[i] = f2bf(a[i] + b[i]);
}

__global__ void k_addcvt2(const u16* __restrict__ a, const float* __restrict__ b,
                          u16* __restrict__ o, int n) {
    int i = blockIdx.x * blockDim.x + threadIdx.x;
    if (i < n) o[i] = f2bf(bf2f(a[i]) + b[i]);
}

// ---------------- GEMM: Y = X @ W^T + bias (MFMA bf16) ----------------
__device__ __forceinline__ bf16x8 loadx(const u16* p) { return *(const bf16x8*)p; }
__device__ __forceinline__ bf16x8 loadx(const float* p) {
    float4 a = *(const float4*)p;
    float4 b = *(const float4*)(p + 4);
    union { bf16x8 v; u16 s[8]; } r;
    r.s[0] = f2bf(a.x); r.s[1] = f2bf(a.y); r.s[2] = f2bf(a.z); r.s[3] = f2bf(a.w);
    r.s[4] = f2bf(b.x); r.s[5] = f2bf(b.y); r.s[6] = f2bf(b.z); r.s[7] = f2bf(b.w);
    return r.v;
}
__device__ __forceinline__ void storey(float* p, float v) { *p = v; }
__device__ __forceinline__ void storey(u16* p, float v)   { *p = f2bf(v); }

// 128x128 tile, BK=32, 256 threads = 4 waves (2x2), each wave 64x64 (4x4 frags).
template <typename XT, typename OT, bool RELU>
__global__ __launch_bounds__(256) void k_gemm(
    const XT* __restrict__ X, const u16* __restrict__ W,
    const float* __restrict__ bias, OT* __restrict__ Y,
    int M, int N, int K)
{
    __shared__ u16 As[128 * 40];   // 40-elem stride: 16B-aligned rows, banks spread
    __shared__ u16 Bs[128 * 40];
    const int tid = threadIdx.x;
    const int wave = tid >> 6, lane = tid & 63;
    const int wr = wave >> 1, wc = wave & 1;
    const int fr = lane & 15, fg = lane >> 4;
    const int bm = blockIdx.x * 128, bn = blockIdx.y * 128;
    const int srow = tid >> 2, sc = (tid & 3) * 8;

    f32x4 acc[4][4];
    #pragma unroll
    for (int m = 0; m < 4; ++m)
        #pragma unroll
        for (int n = 0; n < 4; ++n) acc[m][n] = (f32x4){0.f, 0.f, 0.f, 0.f};

    for (int k0 = 0; k0 < K; k0 += 32) {
        __syncthreads();
        #pragma unroll
        for (int i = 0; i < 2; ++i) {
            int row = srow + i * 64;
            int gr = bm + row; if (gr > M - 1) gr = M - 1;
            bf16x8 xa = loadx(X + (size_t)gr * K + k0 + sc);
            *(bf16x8*)&As[row * 40 + sc] = xa;
            bf16x8 wb = *(const bf16x8*)(W + (size_t)(bn + row) * K + k0 + sc);
            *(bf16x8*)&Bs[row * 40 + sc] = wb;
        }
        __syncthreads();
        bf16x8 af[4], bg[4];
        #pragma unroll
        for (int m = 0; m < 4; ++m)
            af[m] = *(const bf16x8*)&As[(wr * 64 + m * 16 + fr) * 40 + fg * 8];
        #pragma unroll
        for (int n = 0; n < 4; ++n)
            bg[n] = *(const bf16x8*)&Bs[(wc * 64 + n * 16 + fr) * 40 + fg * 8];
        #pragma unroll
        for (int m = 0; m < 4; ++m)
            #pragma unroll
            for (int n = 0; n < 4; ++n)
                acc[m][n] = mfma_bf16(af[m], bg[n], acc[m][n]);
    }

    #pragma unroll
    for (int m = 0; m < 4; ++m) {
        #pragma unroll
        for (int i = 0; i < 4; ++i) {
            int grow = bm + wr * 64 + m * 16 + fg * 4 + i;
            if (grow >= M) continue;
            #pragma unroll
            for (int n = 0; n < 4; ++n) {
                int gcol = bn + wc * 64 + n * 16 + fr;
                float v = acc[m][n][i] + bias[gcol];
                if (RELU) v = fmaxf(v, 0.f);
                storey(Y + (size_t)grow * N + gcol, v);
            }
        }
    }
}

// ---------------- flash self-attention (MFMA bf16) ----------------
__global__ __launch_bounds__(256) void k_attn(
    const u16* __restrict__ Q, const u16* __restrict__ K,
    const u16* __restrict__ V, u16* __restrict__ O)
{
    __shared__ u16 Ks[64 * 40];       // [key][dh], stride 40
    __shared__ u16 Vt[32 * 72];       // [dh][kv],  stride 72
    __shared__ u16 Ps[4 * 16 * 72];   // per-wave [q][kv], stride 72
    const int b = blockIdx.z, h = blockIdx.y;
    const int q0 = blockIdx.x * 64;
    const int tid = threadIdx.x;
    const int wave = tid >> 6, lane = tid & 63;
    const int fr = lane & 15, fg = lane >> 4;
    u16* Pw = &Ps[wave * 16 * 72];

    int qg = q0 + wave * 16 + fr; if (qg >= LQ_) qg = LQ_ - 1;
    const bf16x8 qf = *(const bf16x8*)&Q[((size_t)(b * LQ_ + qg)) * 256 + h * 32 + fg * 8];

    f32x4 o0 = (f32x4){0.f,0.f,0.f,0.f}, o1 = (f32x4){0.f,0.f,0.f,0.f};
    float m_run = -1e30f, l_run = 0.f;

    const int key_t = tid >> 2, kc8 = (tid & 3) * 8;   // K staging
    const int vkv = tid & 63, vdh = (tid >> 6) * 8;    // V staging (transpose)

    for (int kb0 = 0; kb0 < LQ_; kb0 += 64) {
        __syncthreads();
        {
            int kg = kb0 + key_t; if (kg >= LQ_) kg = LQ_ - 1;
            bf16x8 kv = *(const bf16x8*)&K[((size_t)(b * LQ_ + kg)) * 256 + h * 32 + kc8];
            *(bf16x8*)&Ks[key_t * 40 + kc8] = kv;
            int vg = kb0 + vkv; if (vg >= LQ_) vg = LQ_ - 1;
            union { bf16x8 v; u16 s[8]; } vv;
            vv.v = *(const bf16x8*)&V[((size_t)(b * LQ_ + vg)) * 256 + h * 32 + vdh];
            #pragma unroll
            for (int j = 0; j < 8; ++j) Vt[(vdh + j) * 72 + vkv] = vv.s[j];
        }
        __syncthreads();

        f32x4 st[4];
        #pragma unroll
        for (int f = 0; f < 4; ++f) {
            bf16x8 ka = *(const bf16x8*)&Ks[(f * 16 + fr) * 40 + fg * 8];
            st[f] = mfma_bf16(ka, qf, (f32x4){0.f,0.f,0.f,0.f});
        }

        float mx = -1e30f;
        #pragma unroll
        for (int f = 0; f < 4; ++f) {
            #pragma unroll
            for (int i = 0; i < 4; ++i) {
                int key = kb0 + f * 16 + fg * 4 + i;
                float s = st[f][i] * SCALE_;
                s = (key < LQ_) ? s : -1e30f;
                st[f][i] = s;
                mx = fmaxf(mx, s);
            }
        }
        mx = fmaxf(mx, __shfl_xor(mx, 16));
        mx = fmaxf(mx, __shfl_xor(mx, 32));
        float mnew = fmaxf(m_run, mx);
        float fac = __expf(m_run - mnew);

        float psum = 0.f;
        u32 pw[8];
        #pragma unroll
        for (int f = 0; f < 4; ++f) {
            float p0 = __expf(st[f][0] - mnew), p1 = __expf(st[f][1] - mnew);
            float p2 = __expf(st[f][2] - mnew), p3 = __expf(st[f][3] - mnew);
            psum += (p0 + p1) + (p2 + p3);
            pw[f * 2 + 0] = (u32)f2bf(p0) | ((u32)f2bf(p1) << 16);
            pw[f * 2 + 1] = (u32)f2bf(p2) | ((u32)f2bf(p3) << 16);
        }
        psum += __shfl_xor(psum, 16);
        psum += __shfl_xor(psum, 32);
        l_run = l_run * fac + psum;
        m_run = mnew;
        #pragma unroll
        for (int i = 0; i < 4; ++i) { o0[i] *= fac; o1[i] *= fac; }

        #pragma unroll
        for (int f = 0; f < 4; ++f) {
            *(u32*)&Pw[fr * 72 + f * 16 + fg * 4]     = pw[f * 2 + 0];
            *(u32*)&Pw[fr * 72 + f * 16 + fg * 4 + 2] = pw[f * 2 + 1];
        }
        asm volatile("s_waitcnt lgkmcnt(0)" ::: "memory");

        #pragma unroll
        for (int ks = 0; ks < 2; ++ks) {
            bf16x8 pb  = *(const bf16x8*)&Pw[fr * 72 + ks * 32 + fg * 8];
            bf16x8 va0 = *(const bf16x8*)&Vt[fr * 72 + ks * 32 + fg * 8];
            bf16x8 va1 = *(const bf16x8*)&Vt[(16 + fr) * 72 + ks * 32 + fg * 8];
            o0 = mfma_bf16(va0, pb, o0);
            o1 = mfma_bf16(va1, pb, o1);
        }
    }

    float inv = 1.f / l_run;
    int qout = q0 + wave * 16 + fr;
    if (qout < LQ_) {
        size_t base = ((size_t)(b * LQ_ + qout)) * 256 + h * 32;
        #pragma unroll
        for (int i = 0; i < 4; ++i) {
            O[base + fg * 4 + i]      = f2bf(o0[i] * inv);
            O[base + 16 + fg * 4 + i] = f2bf(o1[i] * inv);
        }
    }
}

// ---------------- residual + LayerNorm ----------------
__device__ __forceinline__ float ldf(const float* p) { return *p; }
__device__ __forceinline__ float ldf(const u16* p)   { return bf2f(*p); }

template <typename RT, typename OT>
__global__ __launch_bounds__(256) void k_resln(
    const u16* __restrict__ X, const RT* __restrict__ R,
    const float* __restrict__ g, const float* __restrict__ bb,
    OT* __restrict__ O)
{
    const int row = blockIdx.x;
    const int d = threadIdx.x;
    const size_t off = (size_t)row * D_ + d;
    float v = ldf(R + off) + bf2f(X[off]);
    __shared__ float r1[4], r2[4];
    int lane = d & 63, wid = d >> 6;
    float s = v;
    #pragma unroll
    for (int o_ = 32; o_ >= 1; o_ >>= 1) s += __shfl_xor(s, o_);
    if (lane == 0) r1[wid] = s;
    __syncthreads();
    float mean = (r1[0] + r1[1] + r1[2] + r1[3]) * (1.f / 256.f);
    float dv = v - mean;
    float sq = dv * dv;
    #pragma unroll
    for (int o_ = 32; o_ >= 1; o_ >>= 1) sq += __shfl_xor(sq, o_);
    if (lane == 0) r2[wid] = sq;
    __syncthreads();
    float var = (r2[0] + r2[1] + r2[2] + r2[3]) * (1.f / 256.f);
    storey(O + off, dv / sqrtf(var + 1e-5f) * g[d] + bb[d]);
}

// ---------------- deformable sampling (two-phase, LDS precompute) ----------------
// Block = 256 threads handles 2 queries. Phase 1: one thread per (query,h,l,p)
// sample point: aw-softmax in-register (16-lane shfl group), coord math once,
// fold aw into 4 corner weights, write {4 offsets, 4 weights} to LDS.
// Phase 2: thread = (query, h, dh-pair): 64 u32 gathers (2 bf16 each).
// LDS point index = lp*8 + h so phase-2's 4 concurrent h-addresses are 32B
// apart (banks 0/8/16/24, conflict-free broadcast reads).
__global__ __launch_bounds__(256) void k_sample(
    const float* __restrict__ offs, const float* __restrict__ aw,
    const u16* __restrict__ value, const float* __restrict__ refp,
    u16* __restrict__ acc_out)
{
    __shared__ u32 pts[2][128][8];   // [qsub][lp*8+h][0..3 off, 4..7 w]
    const int t = threadIdx.x;
    const int bq0 = blockIdx.x * 2;          // 2 queries, same batch (LQ even)
    const int b = bq0 / LQ_;

    constexpr int Hl[4] = {100, 50, 25, 13};
    constexpr int Wl[4] = {150, 75, 38, 19};
    constexpr int LS[4] = {0, 15000, 18750, 19700};

    // ---- phase 1 ----
    {
        const int qsub = t >> 7;
        const int pt = t & 127;
        const int h = pt >> 4, lp = pt & 15;
        const int l = lp >> 2, p = lp & 3;
        const int bq = bq0 + qsub;

        float2 oxy = *(const float2*)&offs[(size_t)bq * 256 + h * 32 + l * 8 + p * 2];
        float av = aw[(size_t)bq * 128 + h * 16 + lp];
        // softmax over the 16-lane (l,p) group of this head
        float mx = av;
        #pragma unroll
        for (int s = 1; s < 16; s <<= 1) mx = fmaxf(mx, __shfl_xor(mx, s));
        float e = __expf(av - mx);
        float sum = e;
        #pragma unroll
        for (int s = 1; s < 16; s <<= 1) sum += __shfl_xor(sum, s);
        float a = e / sum;

        float2 rxy = *(const float2*)&refp[(size_t)bq * 8 + l * 2];
        const float Wf = (float)Wl[l], Hf = (float)Hl[l];
        float x = (rxy.x + oxy.x / Wf) * Wf - 0.5f;
        float y = (rxy.y + oxy.y / Hf) * Hf - 0.5f;
        float x0f = floorf(x), y0f = floorf(y);
        int x0 = (int)x0f, y0 = (int)y0f;
        float wx1 = x - x0f, wy1 = y - y0f;
        float wx0 = 1.f - wx1, wy0 = 1.f - wy1;

        u32 ov[4]; float wv[4];
        #pragma unroll
        for (int c = 0; c < 4; ++c) {
            int cy = c >> 1, cx = c & 1;
            int yi = y0 + cy, xi = x0 + cx;
            bool valid = (yi >= 0) && (yi < Hl[l]) && (xi >= 0) && (xi < Wl[l]);
            ov[c] = valid ? (u32)((LS[l] + yi * Wl[l] + xi) * 256 + h * 32) : 0u;
            float w = (cy ? wy1 : wy0) * (cx ? wx1 : wx0) * a;
            wv[c] = valid ? w : 0.f;
        }
        u32* dst = pts[qsub][lp * 8 + h];
        *(uint4*)dst = make_uint4(ov[0], ov[1], ov[2], ov[3]);
        float4 wq = make_float4(wv[0], wv[1], wv[2], wv[3]);
        *(float4*)(dst + 4) = wq;
    }
    __syncthreads();

    // ---- phase 2 ----
    const int qsub = t >> 7;
    const int h = (t >> 4) & 7;
    const int dp = t & 15;                    // dh pair: dh = 2*dp, 2*dp+1
    const u16* vb = value + (size_t)b * LIN_ * 256 + 2 * dp;
    float a0 = 0.f, a1 = 0.f;
    #pragma unroll
    for (int i = 0; i < 16; ++i) {
        const u32* P = pts[qsub][i * 8 + h];
        uint4 o4 = *(const uint4*)P;
        float4 w4 = *(const float4*)(P + 4);
        u32 g;
        g = *(const u32*)&vb[o4.x]; a0 += w4.x * bf2f((u16)g); a1 += w4.x * bf2f((u16)(g >> 16));
        g = *(const u32*)&vb[o4.y]; a0 += w4.y * bf2f((u16)g); a1 += w4.y * bf2f((u16)(g >> 16));
        g = *(const u32*)&vb[o4.z]; a0 += w4.z * bf2f((u16)g); a1 += w4.z * bf2f((u16)(g >> 16));
        g = *(const u32*)&vb[o4.w]; a0 += w4.w * bf2f((u16)g); a1 += w4.w * bf2f((u16)(g >> 16));
    }
    const int bq = bq0 + qsub;
    u32 packed = (u32)f2bf(a0) | ((u32)f2bf(a1) << 16);
    *(u32*)&acc_out[(size_t)bq * 256 + h * 32 + 2 * dp] = packed;
}

// ---------------- launch ----------------
extern "C" void kernel_launch(void* const* d_in, const int* in_sizes, int n_in,
                              void* d_out, int out_size, void* d_ws, size_t ws_size,
                              hipStream_t stream)
{
    (void)in_sizes; (void)n_in; (void)out_size; (void)ws_size;
    const float* tgt   = (const float*)d_in[0];
    const float* qpos  = (const float*)d_in[1];
    const float* refp  = (const float*)d_in[2];
    const float* src   = (const float*)d_in[3];
    const float* qW    = (const float*)d_in[4];
    const float* qb    = (const float*)d_in[5];
    const float* kW    = (const float*)d_in[6];
    const float* kb    = (const float*)d_in[7];
    const float* vW    = (const float*)d_in[8];
    const float* vb    = (const float*)d_in[9];
    const float* oW    = (const float*)d_in[10];
    const float* ob    = (const float*)d_in[11];
    const float* a_q   = (const float*)d_in[12];
    const float* a_k   = (const float*)d_in[13];
    const float* a_v   = (const float*)d_in[14];
    const float* a_o   = (const float*)d_in[15];
    const float* val_W = (const float*)d_in[16];
    const float* val_b = (const float*)d_in[17];
    const float* a_val = (const float*)d_in[18];
    const float* off_W = (const float*)d_in[19];
    const float* off_b = (const float*)d_in[20];
    const float* aw_W  = (const float*)d_in[21];
    const float* aw_b  = (const float*)d_in[22];
    const float* out_W = (const float*)d_in[23];
    const float* out_b = (const float*)d_in[24];
    const float* a_out = (const float*)d_in[25];
    const float* W1    = (const float*)d_in[26];
    const float* b1    = (const float*)d_in[27];
    const float* a_w1  = (const float*)d_in[28];
    const float* W2    = (const float*)d_in[29];
    const float* b2    = (const float*)d_in[30];
    const float* a_w2  = (const float*)d_in[31];
    const float* ln1_g = (const float*)d_in[32];
    const float* ln1_b = (const float*)d_in[33];
    const float* ln2_g = (const float*)d_in[34];
    const float* ln2_b = (const float*)d_in[35];
    const float* ln3_g = (const float*)d_in[36];
    const float* ln3_b = (const float*)d_in[37];

    // ---- workspace layout ----
    u16* wq_q  = (u16*)d_ws;
    u16* wq_k  = wq_q + 65536;
    u16* wq_v  = wq_k + 65536;
    u16* wq_o  = wq_v + 65536;
    u16* wq_vl = wq_o + 65536;
    u16* wq_ot = wq_vl + 65536;
    u16* w_off = wq_ot + 65536;
    u16* w_aw  = w_off + 65536;
    u16* wq_1  = w_aw + 32768;
    u16* wq_2  = wq_1 + 262144;
    u16* bufA  = wq_2 + 262144;      // NELEM bf16 each
    u16* bufB  = bufA + NELEM_;
    u16* bufC  = bufB + NELEM_;
    u16* bufD  = bufC + NELEM_;
    u16* bufE  = bufD + NELEM_;
    float* offs = (float*)(bufE + NELEM_);   // NELEM f32
    float* awb  = offs + NELEM_;             // MQ*128 f32
    u16* valb   = (u16*)(awb + MQ_ * 128);   // B*LIN*256 bf16 (later reused as ffn1)

    const int TB = 256;
    const int MVAL = B_ * LIN_;

    // weights
    k_quant<<<CDIV(65536, TB), TB, 0, stream>>>(qW, a_q, wq_q, 65536);
    k_quant<<<CDIV(65536, TB), TB, 0, stream>>>(kW, a_k, wq_k, 65536);
    k_quant<<<CDIV(65536, TB), TB, 0, stream>>>(vW, a_v, wq_v, 65536);
    k_quant<<<CDIV(65536, TB), TB, 0, stream>>>(oW, a_o, wq_o, 65536);
    k_quant<<<CDIV(65536, TB), TB, 0, stream>>>(val_W, a_val, wq_vl, 65536);
    k_quant<<<CDIV(65536, TB), TB, 0, stream>>>(out_W, a_out, wq_ot, 65536);
    k_quant<<<CDIV(262144, TB), TB, 0, stream>>>(W1, a_w1, wq_1, 262144);
    k_quant<<<CDIV(262144, TB), TB, 0, stream>>>(W2, a_w2, wq_2, 262144);
    k_cvt<<<CDIV(65536, TB), TB, 0, stream>>>(off_W, w_off, 65536);
    k_cvt<<<CDIV(32768, TB), TB, 0, stream>>>(aw_W, w_aw, 32768);

    // activation prep
    k_addcvt<<<CDIV(NELEM_, TB), TB, 0, stream>>>(tgt, qpos, bufA, NELEM_);  // qk_in
    k_cvt<<<CDIV(NELEM_, TB), TB, 0, stream>>>(tgt, bufB, NELEM_);           // tgt_bf

    // ---- self-attention ----
    k_gemm<u16, u16, false><<<dim3(CDIV(MQ_,128), 2), TB, 0, stream>>>(bufA, wq_q, qb, bufC, MQ_, 256, 256);
    k_gemm<u16, u16, false><<<dim3(CDIV(MQ_,128), 2), TB, 0, stream>>>(bufA, wq_k, kb, bufD, MQ_, 256, 256);
    k_gemm<u16, u16, false><<<dim3(CDIV(MQ_,128), 2), TB, 0, stream>>>(bufB, wq_v, vb, bufE, MQ_, 256, 256);
    k_attn<<<dim3(CDIV(LQ_,64), H_, B_), TB, 0, stream>>>(bufC, bufD, bufE, bufA);       // sa -> A
    k_gemm<u16, u16, false><<<dim3(CDIV(MQ_,128), 2), TB, 0, stream>>>(bufA, wq_o, ob, bufB, MQ_, 256, 256);
    k_resln<float, u16><<<MQ_, TB, 0, stream>>>(bufB, tgt, ln2_g, ln2_b, bufC);          // tgt2 -> C

    // ---- deformable cross-attention ----
    k_addcvt2<<<CDIV(NELEM_, TB), TB, 0, stream>>>(bufC, qpos, bufD, NELEM_);            // query -> D
    k_gemm<float, u16, false><<<dim3(CDIV(MVAL,128), 2), TB, 0, stream>>>(src, wq_vl, val_b, valb, MVAL, 256, 256);
    k_gemm<u16, float, false><<<dim3(CDIV(MQ_,128), 2), TB, 0, stream>>>(bufD, w_off, off_b, offs, MQ_, 256, 256);
    k_gemm<u16, float, false><<<dim3(CDIV(MQ_,128), 1), TB, 0, stream>>>(bufD, w_aw, aw_b, awb, MQ_, 128, 256);
    k_sample<<<MQ_ / 2, TB, 0, stream>>>(offs, awb, valb, refp, bufE);                   // acc -> E
    k_gemm<u16, u16, false><<<dim3(CDIV(MQ_,128), 2), TB, 0, stream>>>(bufE, wq_ot, out_b, bufA, MQ_, 256, 256);
    k_resln<u16, u16><<<MQ_, TB, 0, stream>>>(bufA, bufC, ln1_g, ln1_b, bufB);           // tgt3 -> B

    // ---- FFN ----
    u16* ffn1 = valb;  // value dead after k_sample
    k_gemm<u16, u16, true ><<<dim3(CDIV(MQ_,128), 8), TB, 0, stream>>>(bufB, wq_1, b1, ffn1, MQ_, 1024, 256);
    k_gemm<u16, u16, false><<<dim3(CDIV(MQ_,128), 2), TB, 0, stream>>>(ffn1, wq_2, b2, bufD, MQ_, 256, 1024);
    k_resln<u16, float><<<MQ_, TB, 0, stream>>>(bufD, bufB, ln3_g, ln3_b, (float*)d_out);
}

// Round 4
// 447.250 us; speedup vs baseline: 3.9969x; 1.1344x over previous
//
#include <hip/hip_runtime.h>
#include <hip/hip_bf16.h>

// ---------------- constants ----------------
static constexpr int B_   = 8;
static constexpr int LQ_  = 1800;
static constexpr int D_   = 256;
static constexpr int H_   = 8;
static constexpr int DFF_ = 1024;
static constexpr int LIN_ = 19947;
static constexpr int MQ_  = B_ * LQ_;       // 14400
static constexpr int NELEM_ = MQ_ * D_;     // 3,686,400

#define CDIV(a, b) (((a) + (b) - 1) / (b))

typedef unsigned short u16;
typedef unsigned int   u32;
typedef unsigned long long u64;
typedef __attribute__((ext_vector_type(8))) __bf16 bf16x8;
typedef __attribute__((ext_vector_type(4))) float  f32x4;

// ---------------- bf16 helpers (RNE via native cast -> v_cvt_pk_bf16_f32) ----
__device__ __forceinline__ u16 f2bf(float f) {
    union { __bf16 h; u16 u; } v; v.h = (__bf16)f; return v.u;
}
__device__ __forceinline__ float bf2f(u16 u) {
    union { u32 u; float f; } v; v.u = ((u32)u) << 16;
    return v.f;
}

__device__ __forceinline__ f32x4 mfma_bf16(bf16x8 a, bf16x8 b, f32x4 c) {
    return __builtin_amdgcn_mfma_f32_16x16x32_bf16(a, b, c, 0, 0, 0);
}

// ---------------- small elementwise kernels ----------------
__global__ void k_quant(const float* __restrict__ w, const float* __restrict__ alpha,
                        u16* __restrict__ o, int n) {
    int i = blockIdx.x * blockDim.x + threadIdx.x;
    if (i >= n) return;
    float a = alpha[0];
    float wn = fminf(fmaxf(w[i] / a, -8.f), 7.f);
    o[i] = f2bf(rintf(wn) * a);
}

__global__ void k_cvt(const float* __restrict__ w, u16* __restrict__ o, int n) {
    int i = blockIdx.x * blockDim.x + threadIdx.x;
    if (i < n) o[i] = f2bf(w[i]);
}

__global__ void k_addcvt(const float* __restrict__ a, const float* __restrict__ b,
                         u16* __restrict__ o, int n) {
    int i = blockIdx.x * blockDim.x + threadIdx.x;
    if (i < n) o[i] = f2bf(a[i] + b[i]);
}

__global__ void k_addcvt2(const u16* __restrict__ a, const float* __restrict__ b,
                          u16* __restrict__ o, int n) {
    int i = blockIdx.x * blockDim.x + threadIdx.x;
    if (i < n) o[i] = f2bf(bf2f(a[i]) + b[i]);
}

// ---------------- GEMM: Y = X @ W^T + bias (MFMA bf16) ----------------
__device__ __forceinline__ bf16x8 loadx(const u16* p) { return *(const bf16x8*)p; }
__device__ __forceinline__ bf16x8 loadx(const float* p) {
    float4 a = *(const float4*)p;
    float4 b = *(const float4*)(p + 4);
    bf16x8 r;
    r[0] = (__bf16)a.x; r[1] = (__bf16)a.y; r[2] = (__bf16)a.z; r[3] = (__bf16)a.w;
    r[4] = (__bf16)b.x; r[5] = (__bf16)b.y; r[6] = (__bf16)b.z; r[7] = (__bf16)b.w;
    return r;
}
__device__ __forceinline__ void storey(float* p, float v) { *p = v; }
__device__ __forceinline__ void storey(u16* p, float v)   { *p = f2bf(v); }

// 128x128 tile, BK=32, 256 threads = 4 waves (2x2), each wave 64x64 (4x4 frags).
template <typename XT, typename OT, bool RELU>
__global__ __launch_bounds__(256) void k_gemm(
    const XT* __restrict__ X, const u16* __restrict__ W,
    const float* __restrict__ bias, OT* __restrict__ Y,
    int M, int N, int K)
{
    __shared__ u16 As[128 * 40];   // 40-elem stride: 16B-aligned rows, banks spread
    __shared__ u16 Bs[128 * 40];
    const int tid = threadIdx.x;
    const int wave = tid >> 6, lane = tid & 63;
    const int wr = wave >> 1, wc = wave & 1;
    const int fr = lane & 15, fg = lane >> 4;
    const int bm = blockIdx.x * 128, bn = blockIdx.y * 128;
    const int srow = tid >> 2, sc = (tid & 3) * 8;

    f32x4 acc[4][4];
    #pragma unroll
    for (int m = 0; m < 4; ++m)
        #pragma unroll
        for (int n = 0; n < 4; ++n) acc[m][n] = (f32x4){0.f, 0.f, 0.f, 0.f};

    for (int k0 = 0; k0 < K; k0 += 32) {
        __syncthreads();
        #pragma unroll
        for (int i = 0; i < 2; ++i) {
            int row = srow + i * 64;
            int gr = bm + row; if (gr > M - 1) gr = M - 1;
            bf16x8 xa = loadx(X + (size_t)gr * K + k0 + sc);
            *(bf16x8*)&As[row * 40 + sc] = xa;
            bf16x8 wb = *(const bf16x8*)(W + (size_t)(bn + row) * K + k0 + sc);
            *(bf16x8*)&Bs[row * 40 + sc] = wb;
        }
        __syncthreads();
        bf16x8 af[4], bg[4];
        #pragma unroll
        for (int m = 0; m < 4; ++m)
            af[m] = *(const bf16x8*)&As[(wr * 64 + m * 16 + fr) * 40 + fg * 8];
        #pragma unroll
        for (int n = 0; n < 4; ++n)
            bg[n] = *(const bf16x8*)&Bs[(wc * 64 + n * 16 + fr) * 40 + fg * 8];
        #pragma unroll
        for (int m = 0; m < 4; ++m)
            #pragma unroll
            for (int n = 0; n < 4; ++n)
                acc[m][n] = mfma_bf16(af[m], bg[n], acc[m][n]);
    }

    #pragma unroll
    for (int m = 0; m < 4; ++m) {
        #pragma unroll
        for (int i = 0; i < 4; ++i) {
            int grow = bm + wr * 64 + m * 16 + fg * 4 + i;
            if (grow >= M) continue;
            #pragma unroll
            for (int n = 0; n < 4; ++n) {
                int gcol = bn + wc * 64 + n * 16 + fr;
                float v = acc[m][n][i] + bias[gcol];
                if (RELU) v = fmaxf(v, 0.f);
                storey(Y + (size_t)grow * N + gcol, v);
            }
        }
    }
}

// ---------------- flash self-attention v2 (MFMA bf16, KVBLK=128) ----------------
// Block = 256 thr = 4 waves; 64 queries/block (wave owns 16 via fr).
// Raw-domain running max; p = exp(fma(s, C1, -m*C1)); defer-max (p<=256);
// tail guard only in last tile; P packed via native bf16 casts -> ds_write_b64.
__global__ __launch_bounds__(256) void k_attn(
    const u16* __restrict__ Q, const u16* __restrict__ K,
    const u16* __restrict__ V, u16* __restrict__ O)
{
    __shared__ u16 Ks[128 * 40];       // [key][dh], stride 40
    __shared__ u16 Vt[32 * 136];       // [dh][kv],  stride 136
    __shared__ u16 Ps[4 * 16 * 136];   // per-wave [q][kv], stride 136
    const int b = blockIdx.z, h = blockIdx.y;
    const int q0 = blockIdx.x * 64;
    const int tid = threadIdx.x;
    const int wave = tid >> 6, lane = tid & 63;
    const int fr = lane & 15, fg = lane >> 4;
    u16* Pw = &Ps[wave * 16 * 136];
    constexpr float C1 = 0.17677669529663687f;   // 1/sqrt(32)
    constexpr float THR = 5.545177444479562f;    // ln(256): defer bound

    int qg = q0 + wave * 16 + fr; if (qg >= LQ_) qg = LQ_ - 1;
    const bf16x8 qf = *(const bf16x8*)&Q[((size_t)(b * LQ_ + qg)) * 256 + h * 32 + fg * 8];

    f32x4 o0 = (f32x4){0.f,0.f,0.f,0.f}, o1 = (f32x4){0.f,0.f,0.f,0.f};
    float m_run = -1e30f, l_run = 0.f;

    const int kr = tid >> 1, kc = (tid & 1) * 16;   // K staging: row, col16
    const int vp = tid & 63, vdh = (tid >> 6) * 8;  // V staging: kv-pair, dh block

    for (int kb0 = 0; kb0 < LQ_; kb0 += 128) {
        const bool tail = (kb0 + 128 > LQ_);
        __syncthreads();
        {
            int kg = kb0 + kr; if (kg >= LQ_) kg = LQ_ - 1;
            const u16* kp = &K[((size_t)(b * LQ_ + kg)) * 256 + h * 32 + kc];
            *(bf16x8*)&Ks[kr * 40 + kc]     = *(const bf16x8*)kp;
            *(bf16x8*)&Ks[kr * 40 + kc + 8] = *(const bf16x8*)(kp + 8);
            int v0 = kb0 + 2 * vp, v1 = v0 + 1;
            if (v0 >= LQ_) v0 = LQ_ - 1;
            if (v1 >= LQ_) v1 = LQ_ - 1;
            union { bf16x8 v; u16 s[8]; } va, vb2;
            va.v  = *(const bf16x8*)&V[((size_t)(b * LQ_ + v0)) * 256 + h * 32 + vdh];
            vb2.v = *(const bf16x8*)&V[((size_t)(b * LQ_ + v1)) * 256 + h * 32 + vdh];
            #pragma unroll
            for (int j = 0; j < 8; ++j)
                *(u32*)&Vt[(vdh + j) * 136 + 2 * vp] = (u32)va.s[j] | ((u32)vb2.s[j] << 16);
        }
        __syncthreads();

        // S^T fragments (raw scores): key = kb0 + f*16 + fg*4 + i, q = fr
        f32x4 st[8];
        #pragma unroll
        for (int f = 0; f < 8; ++f) {
            bf16x8 ka = *(const bf16x8*)&Ks[(f * 16 + fr) * 40 + fg * 8];
            st[f] = mfma_bf16(ka, qf, (f32x4){0.f,0.f,0.f,0.f});
        }
        if (tail) {
            #pragma unroll
            for (int f = 0; f < 8; ++f)
                #pragma unroll
                for (int i = 0; i < 4; ++i)
                    if (kb0 + f * 16 + fg * 4 + i >= LQ_) st[f][i] = -3e38f;
        }

        float mx = st[0][0];
        #pragma unroll
        for (int f = 0; f < 8; ++f) {
            mx = fmaxf(mx, fmaxf(fmaxf(st[f][0], st[f][1]), fmaxf(st[f][2], st[f][3])));
        }
        mx = fmaxf(mx, __shfl_xor(mx, 16));
        mx = fmaxf(mx, __shfl_xor(mx, 32));

        // defer-max: only rescale when some row's p would exceed 256
        if (!__all((mx - m_run) * C1 <= THR)) {
            float mnew = fmaxf(m_run, mx);
            float fac = __expf((m_run - mnew) * C1);
            l_run *= fac;
            #pragma unroll
            for (int i = 0; i < 4; ++i) { o0[i] *= fac; o1[i] *= fac; }
            m_run = mnew;
        }

        const float nm = -m_run * C1;
        float psum = 0.f;
        #pragma unroll
        for (int f = 0; f < 8; ++f) {
            float p0 = __expf(fmaf(st[f][0], C1, nm));
            float p1 = __expf(fmaf(st[f][1], C1, nm));
            float p2 = __expf(fmaf(st[f][2], C1, nm));
            float p3 = __expf(fmaf(st[f][3], C1, nm));
            psum += (p0 + p1) + (p2 + p3);
            union { __bf16 h[2]; u32 w; } c0, c1;
            c0.h[0] = (__bf16)p0; c0.h[1] = (__bf16)p1;
            c1.h[0] = (__bf16)p2; c1.h[1] = (__bf16)p3;
            *(u64*)&Pw[fr * 136 + f * 16 + fg * 4] = (u64)c0.w | ((u64)c1.w << 32);
        }
        psum += __shfl_xor(psum, 16);
        psum += __shfl_xor(psum, 32);
        l_run += psum;

        asm volatile("s_waitcnt lgkmcnt(0)" ::: "memory");
        __builtin_amdgcn_sched_barrier(0);

        // PV: O^T(dh,q) += V^T(dh,kv) . P^T(kv,q)
        #pragma unroll
        for (int ks = 0; ks < 4; ++ks) {
            bf16x8 pb  = *(const bf16x8*)&Pw[fr * 136 + ks * 32 + fg * 8];
            bf16x8 va0 = *(const bf16x8*)&Vt[fr * 136 + ks * 32 + fg * 8];
            bf16x8 va1 = *(const bf16x8*)&Vt[(16 + fr) * 136 + ks * 32 + fg * 8];
            o0 = mfma_bf16(va0, pb, o0);
            o1 = mfma_bf16(va1, pb, o1);
        }
    }

    float inv = 1.f / l_run;
    int qout = q0 + wave * 16 + fr;
    if (qout < LQ_) {
        size_t base = ((size_t)(b * LQ_ + qout)) * 256 + h * 32;
        #pragma unroll
        for (int i = 0; i < 4; ++i) {
            O[base + fg * 4 + i]      = f2bf(o0[i] * inv);
            O[base + 16 + fg * 4 + i] = f2bf(o1[i] * inv);
        }
    }
}

// ---------------- residual + LayerNorm ----------------
__device__ __forceinline__ float ldf(const float* p) { return *p; }
__device__ __forceinline__ float ldf(const u16* p)   { return bf2f(*p); }

template <typename RT, typename OT>
__global__ __launch_bounds__(256) void k_resln(
    const u16* __restrict__ X, const RT* __restrict__ R,
    const float* __restrict__ g, const float* __restrict__ bb,
    OT* __restrict__ O)
{
    const int row = blockIdx.x;
    const int d = threadIdx.x;
    const size_t off = (size_t)row * D_ + d;
    float v = ldf(R + off) + bf2f(X[off]);
    __shared__ float r1[4], r2[4];
    int lane = d & 63, wid = d >> 6;
    float s = v;
    #pragma unroll
    for (int o_ = 32; o_ >= 1; o_ >>= 1) s += __shfl_xor(s, o_);
    if (lane == 0) r1[wid] = s;
    __syncthreads();
    float mean = (r1[0] + r1[1] + r1[2] + r1[3]) * (1.f / 256.f);
    float dv = v - mean;
    float sq = dv * dv;
    #pragma unroll
    for (int o_ = 32; o_ >= 1; o_ >>= 1) sq += __shfl_xor(sq, o_);
    if (lane == 0) r2[wid] = sq;
    __syncthreads();
    float var = (r2[0] + r2[1] + r2[2] + r2[3]) * (1.f / 256.f);
    storey(O + off, dv / sqrtf(var + 1e-5f) * g[d] + bb[d]);
}

// ---------------- deformable sampling (two-phase, LDS precompute) ----------------
__global__ __launch_bounds__(256) void k_sample(
    const float* __restrict__ offs, const float* __restrict__ aw,
    const u16* __restrict__ value, const float* __restrict__ refp,
    u16* __restrict__ acc_out)
{
    __shared__ u32 pts[2][128][8];   // [qsub][lp*8+h][0..3 off, 4..7 w]
    const int t = threadIdx.x;
    const int bq0 = blockIdx.x * 2;          // 2 queries, same batch (LQ even)
    const int b = bq0 / LQ_;

    constexpr int Hl[4] = {100, 50, 25, 13};
    constexpr int Wl[4] = {150, 75, 38, 19};
    constexpr int LS[4] = {0, 15000, 18750, 19700};

    // ---- phase 1 ----
    {
        const int qsub = t >> 7;
        const int pt = t & 127;
        const int h = pt >> 4, lp = pt & 15;
        const int l = lp >> 2, p = lp & 3;
        const int bq = bq0 + qsub;

        float2 oxy = *(const float2*)&offs[(size_t)bq * 256 + h * 32 + l * 8 + p * 2];
        float av = aw[(size_t)bq * 128 + h * 16 + lp];
        float mx = av;
        #pragma unroll
        for (int s = 1; s < 16; s <<= 1) mx = fmaxf(mx, __shfl_xor(mx, s));
        float e = __expf(av - mx);
        float sum = e;
        #pragma unroll
        for (int s = 1; s < 16; s <<= 1) sum += __shfl_xor(sum, s);
        float a = e / sum;

        float2 rxy = *(const float2*)&refp[(size_t)bq * 8 + l * 2];
        const float Wf = (float)Wl[l], Hf = (float)Hl[l];
        float x = (rxy.x + oxy.x / Wf) * Wf - 0.5f;
        float y = (rxy.y + oxy.y / Hf) * Hf - 0.5f;
        float x0f = floorf(x), y0f = floorf(y);
        int x0 = (int)x0f, y0 = (int)y0f;
        float wx1 = x - x0f, wy1 = y - y0f;
        float wx0 = 1.f - wx1, wy0 = 1.f - wy1;

        u32 ov[4]; float wv[4];
        #pragma unroll
        for (int c = 0; c < 4; ++c) {
            int cy = c >> 1, cx = c & 1;
            int yi = y0 + cy, xi = x0 + cx;
            bool valid = (yi >= 0) && (yi < Hl[l]) && (xi >= 0) && (xi < Wl[l]);
            ov[c] = valid ? (u32)((LS[l] + yi * Wl[l] + xi) * 256 + h * 32) : 0u;
            float w = (cy ? wy1 : wy0) * (cx ? wx1 : wx0) * a;
            wv[c] = valid ? w : 0.f;
        }
        u32* dst = pts[qsub][lp * 8 + h];
        *(uint4*)dst = make_uint4(ov[0], ov[1], ov[2], ov[3]);
        float4 wq = make_float4(wv[0], wv[1], wv[2], wv[3]);
        *(float4*)(dst + 4) = wq;
    }
    __syncthreads();

    // ---- phase 2 ----
    const int qsub = t >> 7;
    const int h = (t >> 4) & 7;
    const int dp = t & 15;                    // dh pair: dh = 2*dp, 2*dp+1
    const u16* vb = value + (size_t)b * LIN_ * 256 + 2 * dp;
    float a0 = 0.f, a1 = 0.f;
    #pragma unroll
    for (int i = 0; i < 16; ++i) {
        const u32* P = pts[qsub][i * 8 + h];
        uint4 o4 = *(const uint4*)P;
        float4 w4 = *(const float4*)(P + 4);
        u32 g;
        g = *(const u32*)&vb[o4.x]; a0 += w4.x * bf2f((u16)g); a1 += w4.x * bf2f((u16)(g >> 16));
        g = *(const u32*)&vb[o4.y]; a0 += w4.y * bf2f((u16)g); a1 += w4.y * bf2f((u16)(g >> 16));
        g = *(const u32*)&vb[o4.z]; a0 += w4.z * bf2f((u16)g); a1 += w4.z * bf2f((u16)(g >> 16));
        g = *(const u32*)&vb[o4.w]; a0 += w4.w * bf2f((u16)g); a1 += w4.w * bf2f((u16)(g >> 16));
    }
    const int bq = bq0 + qsub;
    u32 packed = (u32)f2bf(a0) | ((u32)f2bf(a1) << 16);
    *(u32*)&acc_out[(size_t)bq * 256 + h * 32 + 2 * dp] = packed;
}

// ---------------- launch ----------------
extern "C" void kernel_launch(void* const* d_in, const int* in_sizes, int n_in,
                              void* d_out, int out_size, void* d_ws, size_t ws_size,
                              hipStream_t stream)
{
    (void)in_sizes; (void)n_in; (void)out_size; (void)ws_size;
    const float* tgt   = (const float*)d_in[0];
    const float* qpos  = (const float*)d_in[1];
    const float* refp  = (const float*)d_in[2];
    const float* src   = (const float*)d_in[3];
    const float* qW    = (const float*)d_in[4];
    const float* qb    = (const float*)d_in[5];
    const float* kW    = (const float*)d_in[6];
    const float* kb    = (const float*)d_in[7];
    const float* vW    = (const float*)d_in[8];
    const float* vb    = (const float*)d_in[9];
    const float* oW    = (const float*)d_in[10];
    const float* ob    = (const float*)d_in[11];
    const float* a_q   = (const float*)d_in[12];
    const float* a_k   = (const float*)d_in[13];
    const float* a_v   = (const float*)d_in[14];
    const float* a_o   = (const float*)d_in[15];
    const float* val_W = (const float*)d_in[16];
    const float* val_b = (const float*)d_in[17];
    const float* a_val = (const float*)d_in[18];
    const float* off_W = (const float*)d_in[19];
    const float* off_b = (const float*)d_in[20];
    const float* aw_W  = (const float*)d_in[21];
    const float* aw_b  = (const float*)d_in[22];
    const float* out_W = (const float*)d_in[23];
    const float* out_b = (const float*)d_in[24];
    const float* a_out = (const float*)d_in[25];
    const float* W1    = (const float*)d_in[26];
    const float* b1    = (const float*)d_in[27];
    const float* a_w1  = (const float*)d_in[28];
    const float* W2    = (const float*)d_in[29];
    const float* b2    = (const float*)d_in[30];
    const float* a_w2  = (const float*)d_in[31];
    const float* ln1_g = (const float*)d_in[32];
    const float* ln1_b = (const float*)d_in[33];
    const float* ln2_g = (const float*)d_in[34];
    const float* ln2_b = (const float*)d_in[35];
    const float* ln3_g = (const float*)d_in[36];
    const float* ln3_b = (const float*)d_in[37];

    // ---- workspace layout ----
    u16* wq_q  = (u16*)d_ws;
    u16* wq_k  = wq_q + 65536;
    u16* wq_v  = wq_k + 65536;
    u16* wq_o  = wq_v + 65536;
    u16* wq_vl = wq_o + 65536;
    u16* wq_ot = wq_vl + 65536;
    u16* w_off = wq_ot + 65536;
    u16* w_aw  = w_off + 65536;
    u16* wq_1  = w_aw + 32768;
    u16* wq_2  = wq_1 + 262144;
    u16* bufA  = wq_2 + 262144;      // NELEM bf16 each
    u16* bufB  = bufA + NELEM_;
    u16* bufC  = bufB + NELEM_;
    u16* bufD  = bufC + NELEM_;
    u16* bufE  = bufD + NELEM_;
    float* offs = (float*)(bufE + NELEM_);   // NELEM f32
    float* awb  = offs + NELEM_;             // MQ*128 f32
    u16* valb   = (u16*)(awb + MQ_ * 128);   // B*LIN*256 bf16 (later reused as ffn1)

    const int TB = 256;
    const int MVAL = B_ * LIN_;

    // weights
    k_quant<<<CDIV(65536, TB), TB, 0, stream>>>(qW, a_q, wq_q, 65536);
    k_quant<<<CDIV(65536, TB), TB, 0, stream>>>(kW, a_k, wq_k, 65536);
    k_quant<<<CDIV(65536, TB), TB, 0, stream>>>(vW, a_v, wq_v, 65536);
    k_quant<<<CDIV(65536, TB), TB, 0, stream>>>(oW, a_o, wq_o, 65536);
    k_quant<<<CDIV(65536, TB), TB, 0, stream>>>(val_W, a_val, wq_vl, 65536);
    k_quant<<<CDIV(65536, TB), TB, 0, stream>>>(out_W, a_out, wq_ot, 65536);
    k_quant<<<CDIV(262144, TB), TB, 0, stream>>>(W1, a_w1, wq_1, 262144);
    k_quant<<<CDIV(262144, TB), TB, 0, stream>>>(W2, a_w2, wq_2, 262144);
    k_cvt<<<CDIV(65536, TB), TB, 0, stream>>>(off_W, w_off, 65536);
    k_cvt<<<CDIV(32768, TB), TB, 0, stream>>>(aw_W, w_aw, 32768);

    // activation prep
    k_addcvt<<<CDIV(NELEM_, TB), TB, 0, stream>>>(tgt, qpos, bufA, NELEM_);  // qk_in
    k_cvt<<<CDIV(NELEM_, TB), TB, 0, stream>>>(tgt, bufB, NELEM_);           // tgt_bf

    // ---- self-attention ----
    k_gemm<u16, u16, false><<<dim3(CDIV(MQ_,128), 2), TB, 0, stream>>>(bufA, wq_q, qb, bufC, MQ_, 256, 256);
    k_gemm<u16, u16, false><<<dim3(CDIV(MQ_,128), 2), TB, 0, stream>>>(bufA, wq_k, kb, bufD, MQ_, 256, 256);
    k_gemm<u16, u16, false><<<dim3(CDIV(MQ_,128), 2), TB, 0, stream>>>(bufB, wq_v, vb, bufE, MQ_, 256, 256);
    k_attn<<<dim3(CDIV(LQ_,64), H_, B_), TB, 0, stream>>>(bufC, bufD, bufE, bufA);       // sa -> A
    k_gemm<u16, u16, false><<<dim3(CDIV(MQ_,128), 2), TB, 0, stream>>>(bufA, wq_o, ob, bufB, MQ_, 256, 256);
    k_resln<float, u16><<<MQ_, TB, 0, stream>>>(bufB, tgt, ln2_g, ln2_b, bufC);          // tgt2 -> C

    // ---- deformable cross-attention ----
    k_addcvt2<<<CDIV(NELEM_, TB), TB, 0, stream>>>(bufC, qpos, bufD, NELEM_);            // query -> D
    k_gemm<float, u16, false><<<dim3(CDIV(MVAL,128), 2), TB, 0, stream>>>(src, wq_vl, val_b, valb, MVAL, 256, 256);
    k_gemm<u16, float, false><<<dim3(CDIV(MQ_,128), 2), TB, 0, stream>>>(bufD, w_off, off_b, offs, MQ_, 256, 256);
    k_gemm<u16, float, false><<<dim3(CDIV(MQ_,128), 1), TB, 0, stream>>>(bufD, w_aw, aw_b, awb, MQ_, 128, 256);
    k_sample<<<MQ_ / 2, TB, 0, stream>>>(offs, awb, valb, refp, bufE);                   // acc -> E
    k_gemm<u16, u16, false><<<dim3(CDIV(MQ_,128), 2), TB, 0, stream>>>(bufE, wq_ot, out_b, bufA, MQ_, 256, 256);
    k_resln<u16, u16><<<MQ_, TB, 0, stream>>>(bufA, bufC, ln1_g, ln1_b, bufB);           // tgt3 -> B

    // ---- FFN ----
    u16* ffn1 = valb;  // value dead after k_sample
    k_gemm<u16, u16, true ><<<dim3(CDIV(MQ_,128), 8), TB, 0, stream>>>(bufB, wq_1, b1, ffn1, MQ_, 1024, 256);
    k_gemm<u16, u16, false><<<dim3(CDIV(MQ_,128), 2), TB, 0, stream>>>(ffn1, wq_2, b2, bufD, MQ_, 256, 1024);
    k_resln<u16, float><<<MQ_, TB, 0, stream>>>(bufD, bufB, ln3_g, ln3_b, (float*)d_out);
}

// Round 5
// 416.506 us; speedup vs baseline: 4.2920x; 1.0738x over previous
//
#include <hip/hip_runtime.h>
#include <hip/hip_bf16.h>

// ---------------- constants ----------------
static constexpr int B_   = 8;
static constexpr int LQ_  = 1800;
static constexpr int D_   = 256;
static constexpr int H_   = 8;
static constexpr int DFF_ = 1024;
static constexpr int LIN_ = 19947;
static constexpr int MQ_  = B_ * LQ_;       // 14400
static constexpr int NELEM_ = MQ_ * D_;     // 3,686,400

#define CDIV(a, b) (((a) + (b) - 1) / (b))

typedef unsigned short u16;
typedef unsigned int   u32;
typedef unsigned long long u64;
typedef __attribute__((ext_vector_type(8))) __bf16 bf16x8;
typedef __attribute__((ext_vector_type(4))) float  f32x4;
typedef __attribute__((ext_vector_type(4))) u32    u32x4;

#if __has_builtin(__builtin_amdgcn_exp2f)
#define EXP2(x) __builtin_amdgcn_exp2f(x)
#else
#define EXP2(x) exp2f(x)
#endif

// ---------------- bf16 helpers (RNE via native cast -> v_cvt_pk_bf16_f32) ----
__device__ __forceinline__ u16 f2bf(float f) {
    union { __bf16 h; u16 u; } v; v.h = (__bf16)f; return v.u;
}
__device__ __forceinline__ float bf2f(u16 u) {
    union { u32 u; float f; } v; v.u = ((u32)u) << 16;
    return v.f;
}

__device__ __forceinline__ f32x4 mfma_bf16(bf16x8 a, bf16x8 b, f32x4 c) {
    return __builtin_amdgcn_mfma_f32_16x16x32_bf16(a, b, c, 0, 0, 0);
}

// ---------------- small elementwise kernels ----------------
__global__ void k_quant(const float* __restrict__ w, const float* __restrict__ alpha,
                        u16* __restrict__ o, int n) {
    int i = blockIdx.x * blockDim.x + threadIdx.x;
    if (i >= n) return;
    float a = alpha[0];
    float wn = fminf(fmaxf(w[i] / a, -8.f), 7.f);
    o[i] = f2bf(rintf(wn) * a);
}

__global__ void k_cvt(const float* __restrict__ w, u16* __restrict__ o, int n) {
    int i = blockIdx.x * blockDim.x + threadIdx.x;
    if (i < n) o[i] = f2bf(w[i]);
}

__global__ void k_addcvt(const float* __restrict__ a, const float* __restrict__ b,
                         u16* __restrict__ o, int n) {
    int i = blockIdx.x * blockDim.x + threadIdx.x;
    if (i < n) o[i] = f2bf(a[i] + b[i]);
}

__global__ void k_addcvt2(const u16* __restrict__ a, const float* __restrict__ b,
                          u16* __restrict__ o, int n) {
    int i = blockIdx.x * blockDim.x + threadIdx.x;
    if (i < n) o[i] = f2bf(bf2f(a[i]) + b[i]);
}

// ---------------- GEMM: Y = X @ W^T + bias (MFMA bf16) ----------------
__device__ __forceinline__ bf16x8 loadx(const u16* p) { return *(const bf16x8*)p; }
__device__ __forceinline__ bf16x8 loadx(const float* p) {
    float4 a = *(const float4*)p;
    float4 b = *(const float4*)(p + 4);
    bf16x8 r;
    r[0] = (__bf16)a.x; r[1] = (__bf16)a.y; r[2] = (__bf16)a.z; r[3] = (__bf16)a.w;
    r[4] = (__bf16)b.x; r[5] = (__bf16)b.y; r[6] = (__bf16)b.z; r[7] = (__bf16)b.w;
    return r;
}
__device__ __forceinline__ void storey(float* p, float v) { *p = v; }
__device__ __forceinline__ void storey(u16* p, float v)   { *p = f2bf(v); }

// 128x128 tile, BK=32, 256 threads = 4 waves (2x2), each wave 64x64 (4x4 frags).
template <typename XT, typename OT, bool RELU>
__global__ __launch_bounds__(256) void k_gemm(
    const XT* __restrict__ X, const u16* __restrict__ W,
    const float* __restrict__ bias, OT* __restrict__ Y,
    int M, int N, int K)
{
    __shared__ u16 As[128 * 40];   // 40-elem stride: 16B-aligned rows, banks spread
    __shared__ u16 Bs[128 * 40];
    const int tid = threadIdx.x;
    const int wave = tid >> 6, lane = tid & 63;
    const int wr = wave >> 1, wc = wave & 1;
    const int fr = lane & 15, fg = lane >> 4;
    const int bm = blockIdx.x * 128, bn = blockIdx.y * 128;
    const int srow = tid >> 2, sc = (tid & 3) * 8;

    f32x4 acc[4][4];
    #pragma unroll
    for (int m = 0; m < 4; ++m)
        #pragma unroll
        for (int n = 0; n < 4; ++n) acc[m][n] = (f32x4){0.f, 0.f, 0.f, 0.f};

    for (int k0 = 0; k0 < K; k0 += 32) {
        __syncthreads();
        #pragma unroll
        for (int i = 0; i < 2; ++i) {
            int row = srow + i * 64;
            int gr = bm + row; if (gr > M - 1) gr = M - 1;
            bf16x8 xa = loadx(X + (size_t)gr * K + k0 + sc);
            *(bf16x8*)&As[row * 40 + sc] = xa;
            bf16x8 wb = *(const bf16x8*)(W + (size_t)(bn + row) * K + k0 + sc);
            *(bf16x8*)&Bs[row * 40 + sc] = wb;
        }
        __syncthreads();
        bf16x8 af[4], bg[4];
        #pragma unroll
        for (int m = 0; m < 4; ++m)
            af[m] = *(const bf16x8*)&As[(wr * 64 + m * 16 + fr) * 40 + fg * 8];
        #pragma unroll
        for (int n = 0; n < 4; ++n)
            bg[n] = *(const bf16x8*)&Bs[(wc * 64 + n * 16 + fr) * 40 + fg * 8];
        #pragma unroll
        for (int m = 0; m < 4; ++m)
            #pragma unroll
            for (int n = 0; n < 4; ++n)
                acc[m][n] = mfma_bf16(af[m], bg[n], acc[m][n]);
    }

    #pragma unroll
    for (int m = 0; m < 4; ++m) {
        #pragma unroll
        for (int i = 0; i < 4; ++i) {
            int grow = bm + wr * 64 + m * 16 + fg * 4 + i;
            if (grow >= M) continue;
            #pragma unroll
            for (int n = 0; n < 4; ++n) {
                int gcol = bn + wc * 64 + n * 16 + fr;
                float v = acc[m][n][i] + bias[gcol];
                if (RELU) v = fmaxf(v, 0.f);
                storey(Y + (size_t)grow * N + gcol, v);
            }
        }
    }
}

// ---------------- flash self-attention v3 (MFMA bf16, KVBLK=128) ----------------
// No max-subtraction (scores are small; softmax is shift-invariant): p = 2^(s'),
// with log2e/sqrt(DH) pre-folded into the Q fragment. Row-sum l accumulated by a
// ones-MFMA on the matrix pipe. P stays entirely in registers: V's LDS columns
// are permuted so the QK C-frag words each lane holds ARE the PV B-frag operand
// in natural order (pb[ks] = bitcast(pq[ks])). No P LDS, no mid-tile waits.
__global__ __launch_bounds__(256) void k_attn(
    const u16* __restrict__ Q, const u16* __restrict__ K,
    const u16* __restrict__ V, u16* __restrict__ O)
{
    __shared__ u16 Ks[128 * 40];       // [key][dh], stride 40
    __shared__ u16 Vt[32 * 136];       // [dh][kv-slot], stride 136 (slot = permuted kv)
    const int b = blockIdx.z, h = blockIdx.y;
    const int q0 = blockIdx.x * 64;
    const int tid = threadIdx.x;
    const int wave = tid >> 6, lane = tid & 63;
    const int fr = lane & 15, fg = lane >> 4;
    constexpr float C2 = 0.25503486f;   // log2(e)/sqrt(32), folded into Q

    int qg = q0 + wave * 16 + fr; if (qg >= LQ_) qg = LQ_ - 1;
    bf16x8 qf;
    {
        bf16x8 qraw = *(const bf16x8*)&Q[((size_t)(b * LQ_ + qg)) * 256 + h * 32 + fg * 8];
        #pragma unroll
        for (int j = 0; j < 8; ++j) qf[j] = (__bf16)((float)qraw[j] * C2);
    }

    const bf16x8 ones = {(__bf16)1.f, (__bf16)1.f, (__bf16)1.f, (__bf16)1.f,
                         (__bf16)1.f, (__bf16)1.f, (__bf16)1.f, (__bf16)1.f};

    f32x4 o0 = (f32x4){0.f,0.f,0.f,0.f}, o1 = (f32x4){0.f,0.f,0.f,0.f};
    f32x4 lacc = (f32x4){0.f,0.f,0.f,0.f};

    const int kr = tid >> 1, kc = (tid & 1) * 16;   // K staging: row, col16
    const int vp = lane, vdh = wave * 8;            // V staging: kv-pair, dh block
    // permuted u32 column for kv-pair vp: cp = (vp5:4, vp2:1, vp3, vp0)
    const int cp = ((vp >> 4) << 4) | (((vp >> 1) & 3) << 2) | (((vp >> 3) & 1) << 1) | (vp & 1);

    for (int kb0 = 0; kb0 < LQ_; kb0 += 128) {
        const bool tail = (kb0 + 128 > LQ_);
        __syncthreads();
        {
            int kg = kb0 + kr; if (kg >= LQ_) kg = LQ_ - 1;
            const u16* kp = &K[((size_t)(b * LQ_ + kg)) * 256 + h * 32 + kc];
            *(bf16x8*)&Ks[kr * 40 + kc]     = *(const bf16x8*)kp;
            *(bf16x8*)&Ks[kr * 40 + kc + 8] = *(const bf16x8*)(kp + 8);
            int v0 = kb0 + 2 * vp, v1 = v0 + 1;
            if (v0 >= LQ_) v0 = LQ_ - 1;
            if (v1 >= LQ_) v1 = LQ_ - 1;
            union { bf16x8 v; u16 s[8]; } va, vb2;
            va.v  = *(const bf16x8*)&V[((size_t)(b * LQ_ + v0)) * 256 + h * 32 + vdh];
            vb2.v = *(const bf16x8*)&V[((size_t)(b * LQ_ + v1)) * 256 + h * 32 + vdh];
            #pragma unroll
            for (int j = 0; j < 8; ++j)
                *(u32*)&Vt[(vdh + j) * 136 + 2 * cp] = (u32)va.s[j] | ((u32)vb2.s[j] << 16);
        }
        __syncthreads();

        // QK + exp: pq[ks] words t=0..3 hold P pairs for kv-pairs (2ks+(t>>1))*8+fg*2+(t&1)
        u32x4 pq[4];
        #pragma unroll
        for (int f = 0; f < 8; ++f) {
            bf16x8 ka = *(const bf16x8*)&Ks[(f * 16 + fr) * 40 + fg * 8];
            f32x4 s = mfma_bf16(ka, qf, (f32x4){0.f,0.f,0.f,0.f});
            if (tail) {
                #pragma unroll
                for (int i = 0; i < 4; ++i)
                    if (kb0 + f * 16 + fg * 4 + i >= LQ_) s[i] = -3e38f;
            }
            float p0 = EXP2(s[0]), p1 = EXP2(s[1]);
            float p2 = EXP2(s[2]), p3 = EXP2(s[3]);
            union { __bf16 h[2]; u32 w; } c0, c1;
            c0.h[0] = (__bf16)p0; c0.h[1] = (__bf16)p1;
            c1.h[0] = (__bf16)p2; c1.h[1] = (__bf16)p3;
            pq[f >> 1][(f & 1) * 2 + 0] = c0.w;
            pq[f >> 1][(f & 1) * 2 + 1] = c1.w;
        }

        // PV + l: O^T(dh,q) += V^T(dh, perm kv) . P^T;  l(q) += sum P
        #pragma unroll
        for (int ks = 0; ks < 4; ++ks) {
            bf16x8 pb  = __builtin_bit_cast(bf16x8, pq[ks]);
            bf16x8 va0 = *(const bf16x8*)&Vt[fr * 136 + ks * 32 + fg * 8];
            bf16x8 va1 = *(const bf16x8*)&Vt[(16 + fr) * 136 + ks * 32 + fg * 8];
            o0 = mfma_bf16(va0, pb, o0);
            o1 = mfma_bf16(va1, pb, o1);
            lacc = mfma_bf16(ones, pb, lacc);
        }
    }

    float inv = 1.f / lacc[0];
    int qout = q0 + wave * 16 + fr;
    if (qout < LQ_) {
        size_t base = ((size_t)(b * LQ_ + qout)) * 256 + h * 32;
        #pragma unroll
        for (int i = 0; i < 4; ++i) {
            O[base + fg * 4 + i]      = f2bf(o0[i] * inv);
            O[base + 16 + fg * 4 + i] = f2bf(o1[i] * inv);
        }
    }
}

// ---------------- residual + LayerNorm ----------------
__device__ __forceinline__ float ldf(const float* p) { return *p; }
__device__ __forceinline__ float ldf(const u16* p)   { return bf2f(*p); }

template <typename RT, typename OT>
__global__ __launch_bounds__(256) void k_resln(
    const u16* __restrict__ X, const RT* __restrict__ R,
    const float* __restrict__ g, const float* __restrict__ bb,
    OT* __restrict__ O)
{
    const int row = blockIdx.x;
    const int d = threadIdx.x;
    const size_t off = (size_t)row * D_ + d;
    float v = ldf(R + off) + bf2f(X[off]);
    __shared__ float r1[4], r2[4];
    int lane = d & 63, wid = d >> 6;
    float s = v;
    #pragma unroll
    for (int o_ = 32; o_ >= 1; o_ >>= 1) s += __shfl_xor(s, o_);
    if (lane == 0) r1[wid] = s;
    __syncthreads();
    float mean = (r1[0] + r1[1] + r1[2] + r1[3]) * (1.f / 256.f);
    float dv = v - mean;
    float sq = dv * dv;
    #pragma unroll
    for (int o_ = 32; o_ >= 1; o_ >>= 1) sq += __shfl_xor(sq, o_);
    if (lane == 0) r2[wid] = sq;
    __syncthreads();
    float var = (r2[0] + r2[1] + r2[2] + r2[3]) * (1.f / 256.f);
    storey(O + off, dv / sqrtf(var + 1e-5f) * g[d] + bb[d]);
}

// ---------------- deformable sampling (two-phase, LDS precompute) ----------------
__global__ __launch_bounds__(256) void k_sample(
    const float* __restrict__ offs, const float* __restrict__ aw,
    const u16* __restrict__ value, const float* __restrict__ refp,
    u16* __restrict__ acc_out)
{
    __shared__ u32 pts[2][128][8];   // [qsub][lp*8+h][0..3 off, 4..7 w]
    const int t = threadIdx.x;
    const int bq0 = blockIdx.x * 2;          // 2 queries, same batch (LQ even)
    const int b = bq0 / LQ_;

    constexpr int Hl[4] = {100, 50, 25, 13};
    constexpr int Wl[4] = {150, 75, 38, 19};
    constexpr int LS[4] = {0, 15000, 18750, 19700};

    // ---- phase 1 ----
    {
        const int qsub = t >> 7;
        const int pt = t & 127;
        const int h = pt >> 4, lp = pt & 15;
        const int l = lp >> 2, p = lp & 3;
        const int bq = bq0 + qsub;

        float2 oxy = *(const float2*)&offs[(size_t)bq * 256 + h * 32 + l * 8 + p * 2];
        float av = aw[(size_t)bq * 128 + h * 16 + lp];
        float mx = av;
        #pragma unroll
        for (int s = 1; s < 16; s <<= 1) mx = fmaxf(mx, __shfl_xor(mx, s));
        float e = __expf(av - mx);
        float sum = e;
        #pragma unroll
        for (int s = 1; s < 16; s <<= 1) sum += __shfl_xor(sum, s);
        float a = e / sum;

        float2 rxy = *(const float2*)&refp[(size_t)bq * 8 + l * 2];
        const float Wf = (float)Wl[l], Hf = (float)Hl[l];
        float x = (rxy.x + oxy.x / Wf) * Wf - 0.5f;
        float y = (rxy.y + oxy.y / Hf) * Hf - 0.5f;
        float x0f = floorf(x), y0f = floorf(y);
        int x0 = (int)x0f, y0 = (int)y0f;
        float wx1 = x - x0f, wy1 = y - y0f;
        float wx0 = 1.f - wx1, wy0 = 1.f - wy1;

        u32 ov[4]; float wv[4];
        #pragma unroll
        for (int c = 0; c < 4; ++c) {
            int cy = c >> 1, cx = c & 1;
            int yi = y0 + cy, xi = x0 + cx;
            bool valid = (yi >= 0) && (yi < Hl[l]) && (xi >= 0) && (xi < Wl[l]);
            ov[c] = valid ? (u32)((LS[l] + yi * Wl[l] + xi) * 256 + h * 32) : 0u;
            float w = (cy ? wy1 : wy0) * (cx ? wx1 : wx0) * a;
            wv[c] = valid ? w : 0.f;
        }
        u32* dst = pts[qsub][lp * 8 + h];
        *(uint4*)dst = make_uint4(ov[0], ov[1], ov[2], ov[3]);
        float4 wq = make_float4(wv[0], wv[1], wv[2], wv[3]);
        *(float4*)(dst + 4) = wq;
    }
    __syncthreads();

    // ---- phase 2 ----
    const int qsub = t >> 7;
    const int h = (t >> 4) & 7;
    const int dp = t & 15;                    // dh pair: dh = 2*dp, 2*dp+1
    const u16* vb = value + (size_t)b * LIN_ * 256 + 2 * dp;
    float a0 = 0.f, a1 = 0.f;
    #pragma unroll
    for (int i = 0; i < 16; ++i) {
        const u32* P = pts[qsub][i * 8 + h];
        uint4 o4 = *(const uint4*)P;
        float4 w4 = *(const float4*)(P + 4);
        u32 g;
        g = *(const u32*)&vb[o4.x]; a0 += w4.x * bf2f((u16)g); a1 += w4.x * bf2f((u16)(g >> 16));
        g = *(const u32*)&vb[o4.y]; a0 += w4.y * bf2f((u16)g); a1 += w4.y * bf2f((u16)(g >> 16));
        g = *(const u32*)&vb[o4.z]; a0 += w4.z * bf2f((u16)g); a1 += w4.z * bf2f((u16)(g >> 16));
        g = *(const u32*)&vb[o4.w]; a0 += w4.w * bf2f((u16)g); a1 += w4.w * bf2f((u16)(g >> 16));
    }
    const int bq = bq0 + qsub;
    u32 packed = (u32)f2bf(a0) | ((u32)f2bf(a1) << 16);
    *(u32*)&acc_out[(size_t)bq * 256 + h * 32 + 2 * dp] = packed;
}

// ---------------- launch ----------------
extern "C" void kernel_launch(void* const* d_in, const int* in_sizes, int n_in,
                              void* d_out, int out_size, void* d_ws, size_t ws_size,
                              hipStream_t stream)
{
    (void)in_sizes; (void)n_in; (void)out_size; (void)ws_size;
    const float* tgt   = (const float*)d_in[0];
    const float* qpos  = (const float*)d_in[1];
    const float* refp  = (const float*)d_in[2];
    const float* src   = (const float*)d_in[3];
    const float* qW    = (const float*)d_in[4];
    const float* qb    = (const float*)d_in[5];
    const float* kW    = (const float*)d_in[6];
    const float* kb    = (const float*)d_in[7];
    const float* vW    = (const float*)d_in[8];
    const float* vb    = (const float*)d_in[9];
    const float* oW    = (const float*)d_in[10];
    const float* ob    = (const float*)d_in[11];
    const float* a_q   = (const float*)d_in[12];
    const float* a_k   = (const float*)d_in[13];
    const float* a_v   = (const float*)d_in[14];
    const float* a_o   = (const float*)d_in[15];
    const float* val_W = (const float*)d_in[16];
    const float* val_b = (const float*)d_in[17];
    const float* a_val = (const float*)d_in[18];
    const float* off_W = (const float*)d_in[19];
    const float* off_b = (const float*)d_in[20];
    const float* aw_W  = (const float*)d_in[21];
    const float* aw_b  = (const float*)d_in[22];
    const float* out_W = (const float*)d_in[23];
    const float* out_b = (const float*)d_in[24];
    const float* a_out = (const float*)d_in[25];
    const float* W1    = (const float*)d_in[26];
    const float* b1    = (const float*)d_in[27];
    const float* a_w1  = (const float*)d_in[28];
    const float* W2    = (const float*)d_in[29];
    const float* b2    = (const float*)d_in[30];
    const float* a_w2  = (const float*)d_in[31];
    const float* ln1_g = (const float*)d_in[32];
    const float* ln1_b = (const float*)d_in[33];
    const float* ln2_g = (const float*)d_in[34];
    const float* ln2_b = (const float*)d_in[35];
    const float* ln3_g = (const float*)d_in[36];
    const float* ln3_b = (const float*)d_in[37];

    // ---- workspace layout ----
    u16* wq_q  = (u16*)d_ws;
    u16* wq_k  = wq_q + 65536;
    u16* wq_v  = wq_k + 65536;
    u16* wq_o  = wq_v + 65536;
    u16* wq_vl = wq_o + 65536;
    u16* wq_ot = wq_vl + 65536;
    u16* w_off = wq_ot + 65536;
    u16* w_aw  = w_off + 65536;
    u16* wq_1  = w_aw + 32768;
    u16* wq_2  = wq_1 + 262144;
    u16* bufA  = wq_2 + 262144;      // NELEM bf16 each
    u16* bufB  = bufA + NELEM_;
    u16* bufC  = bufB + NELEM_;
    u16* bufD  = bufC + NELEM_;
    u16* bufE  = bufD + NELEM_;
    float* offs = (float*)(bufE + NELEM_);   // NELEM f32
    float* awb  = offs + NELEM_;             // MQ*128 f32
    u16* valb   = (u16*)(awb + MQ_ * 128);   // B*LIN*256 bf16 (later reused as ffn1)

    const int TB = 256;
    const int MVAL = B_ * LIN_;

    // weights
    k_quant<<<CDIV(65536, TB), TB, 0, stream>>>(qW, a_q, wq_q, 65536);
    k_quant<<<CDIV(65536, TB), TB, 0, stream>>>(kW, a_k, wq_k, 65536);
    k_quant<<<CDIV(65536, TB), TB, 0, stream>>>(vW, a_v, wq_v, 65536);
    k_quant<<<CDIV(65536, TB), TB, 0, stream>>>(oW, a_o, wq_o, 65536);
    k_quant<<<CDIV(65536, TB), TB, 0, stream>>>(val_W, a_val, wq_vl, 65536);
    k_quant<<<CDIV(65536, TB), TB, 0, stream>>>(out_W, a_out, wq_ot, 65536);
    k_quant<<<CDIV(262144, TB), TB, 0, stream>>>(W1, a_w1, wq_1, 262144);
    k_quant<<<CDIV(262144, TB), TB, 0, stream>>>(W2, a_w2, wq_2, 262144);
    k_cvt<<<CDIV(65536, TB), TB, 0, stream>>>(off_W, w_off, 65536);
    k_cvt<<<CDIV(32768, TB), TB, 0, stream>>>(aw_W, w_aw, 32768);

    // activation prep
    k_addcvt<<<CDIV(NELEM_, TB), TB, 0, stream>>>(tgt, qpos, bufA, NELEM_);  // qk_in
    k_cvt<<<CDIV(NELEM_, TB), TB, 0, stream>>>(tgt, bufB, NELEM_);           // tgt_bf

    // ---- self-attention ----
    k_gemm<u16, u16, false><<<dim3(CDIV(MQ_,128), 2), TB, 0, stream>>>(bufA, wq_q, qb, bufC, MQ_, 256, 256);
    k_gemm<u16, u16, false><<<dim3(CDIV(MQ_,128), 2), TB, 0, stream>>>(bufA, wq_k, kb, bufD, MQ_, 256, 256);
    k_gemm<u16, u16, false><<<dim3(CDIV(MQ_,128), 2), TB, 0, stream>>>(bufB, wq_v, vb, bufE, MQ_, 256, 256);
    k_attn<<<dim3(CDIV(LQ_,64), H_, B_), TB, 0, stream>>>(bufC, bufD, bufE, bufA);       // sa -> A
    k_gemm<u16, u16, false><<<dim3(CDIV(MQ_,128), 2), TB, 0, stream>>>(bufA, wq_o, ob, bufB, MQ_, 256, 256);
    k_resln<float, u16><<<MQ_, TB, 0, stream>>>(bufB, tgt, ln2_g, ln2_b, bufC);          // tgt2 -> C

    // ---- deformable cross-attention ----
    k_addcvt2<<<CDIV(NELEM_, TB), TB, 0, stream>>>(bufC, qpos, bufD, NELEM_);            // query -> D
    k_gemm<float, u16, false><<<dim3(CDIV(MVAL,128), 2), TB, 0, stream>>>(src, wq_vl, val_b, valb, MVAL, 256, 256);
    k_gemm<u16, float, false><<<dim3(CDIV(MQ_,128), 2), TB, 0, stream>>>(bufD, w_off, off_b, offs, MQ_, 256, 256);
    k_gemm<u16, float, false><<<dim3(CDIV(MQ_,128), 1), TB, 0, stream>>>(bufD, w_aw, aw_b, awb, MQ_, 128, 256);
    k_sample<<<MQ_ / 2, TB, 0, stream>>>(offs, awb, valb, refp, bufE);                   // acc -> E
    k_gemm<u16, u16, false><<<dim3(CDIV(MQ_,128), 2), TB, 0, stream>>>(bufE, wq_ot, out_b, bufA, MQ_, 256, 256);
    k_resln<u16, u16><<<MQ_, TB, 0, stream>>>(bufA, bufC, ln1_g, ln1_b, bufB);           // tgt3 -> B

    // ---- FFN ----
    u16* ffn1 = valb;  // value dead after k_sample
    k_gemm<u16, u16, true ><<<dim3(CDIV(MQ_,128), 8), TB, 0, stream>>>(bufB, wq_1, b1, ffn1, MQ_, 1024, 256);
    k_gemm<u16, u16, false><<<dim3(CDIV(MQ_,128), 2), TB, 0, stream>>>(ffn1, wq_2, b2, bufD, MQ_, 256, 1024);
    k_resln<u16, float><<<MQ_, TB, 0, stream>>>(bufD, bufB, ln3_g, ln3_b, (float*)d_out);
}

// Round 6
// 398.552 us; speedup vs baseline: 4.4853x; 1.0450x over previous
//
#include <hip/hip_runtime.h>
#include <hip/hip_bf16.h>

// ---------------- constants ----------------
static constexpr int B_   = 8;
static constexpr int LQ_  = 1800;
static constexpr int D_   = 256;
static constexpr int H_   = 8;
static constexpr int DFF_ = 1024;
static constexpr int LIN_ = 19947;
static constexpr int MQ_  = B_ * LQ_;       // 14400
static constexpr int NELEM_ = MQ_ * D_;     // 3,686,400

#define CDIV(a, b) (((a) + (b) - 1) / (b))

typedef unsigned short u16;
typedef unsigned int   u32;
typedef unsigned long long u64;
typedef __attribute__((ext_vector_type(8))) __bf16 bf16x8;
typedef __attribute__((ext_vector_type(4))) float  f32x4;
typedef __attribute__((ext_vector_type(4))) u32    u32x4;

#if __has_builtin(__builtin_amdgcn_exp2f)
#define EXP2(x) __builtin_amdgcn_exp2f(x)
#else
#define EXP2(x) exp2f(x)
#endif

// ---------------- bf16 helpers (RNE via native cast -> v_cvt_pk_bf16_f32) ----
__device__ __forceinline__ u16 f2bf(float f) {
    union { __bf16 h; u16 u; } v; v.h = (__bf16)f; return v.u;
}
__device__ __forceinline__ float bf2f(u16 u) {
    union { u32 u; float f; } v; v.u = ((u32)u) << 16;
    return v.f;
}

__device__ __forceinline__ f32x4 mfma_bf16(bf16x8 a, bf16x8 b, f32x4 c) {
    return __builtin_amdgcn_mfma_f32_16x16x32_bf16(a, b, c, 0, 0, 0);
}

// ---------------- small elementwise kernels ----------------
__global__ void k_quant(const float* __restrict__ w, const float* __restrict__ alpha,
                        u16* __restrict__ o, int n) {
    int i = blockIdx.x * blockDim.x + threadIdx.x;
    if (i >= n) return;
    float a = alpha[0];
    float wn = fminf(fmaxf(w[i] / a, -8.f), 7.f);
    o[i] = f2bf(rintf(wn) * a);
}

__global__ void k_cvt(const float* __restrict__ w, u16* __restrict__ o, int n) {
    int i = blockIdx.x * blockDim.x + threadIdx.x;
    if (i < n) o[i] = f2bf(w[i]);
}

__global__ void k_addcvt(const float* __restrict__ a, const float* __restrict__ b,
                         u16* __restrict__ o, int n) {
    int i = blockIdx.x * blockDim.x + threadIdx.x;
    if (i < n) o[i] = f2bf(a[i] + b[i]);
}

__global__ void k_addcvt2(const u16* __restrict__ a, const float* __restrict__ b,
                          u16* __restrict__ o, int n) {
    int i = blockIdx.x * blockDim.x + threadIdx.x;
    if (i < n) o[i] = f2bf(bf2f(a[i]) + b[i]);
}

// ---------------- staging-load helpers ----------------
struct rawf8 { float4 a, b; };
__device__ __forceinline__ bf16x8 loadraw(const u16* p) { return *(const bf16x8*)p; }
__device__ __forceinline__ rawf8  loadraw(const float* p) {
    rawf8 r; r.a = *(const float4*)p; r.b = *(const float4*)(p + 4); return r;
}
__device__ __forceinline__ void wlds(u16* d, bf16x8 v) { *(bf16x8*)d = v; }
__device__ __forceinline__ void wlds(u16* d, rawf8 v) {
    bf16x8 r;
    r[0] = (__bf16)v.a.x; r[1] = (__bf16)v.a.y; r[2] = (__bf16)v.a.z; r[3] = (__bf16)v.a.w;
    r[4] = (__bf16)v.b.x; r[5] = (__bf16)v.b.y; r[6] = (__bf16)v.b.z; r[7] = (__bf16)v.b.w;
    *(bf16x8*)d = r;
}
__device__ __forceinline__ void storey(float* p, float v) { *p = v; }
__device__ __forceinline__ void storey(u16* p, float v)   { *p = f2bf(v); }

// ---------------- GEMM v2: Y = X @ W^T + bias (MFMA bf16, dbuf LDS) ----------
// 128x256 tile, BK=32, 512 threads = 8 waves (2x4), wave tile 64x64.
// Double-buffered LDS, next K-tile prefetched into registers during MFMA,
// one barrier per K-step (T3 minimum 2-phase).
template <typename XT, typename OT, bool RELU>
__global__ __launch_bounds__(512) void k_gemm2(
    const XT* __restrict__ X, const u16* __restrict__ W,
    const float* __restrict__ bias, OT* __restrict__ Y,
    int M, int N, int K)
{
    __shared__ u16 As[2][128 * 40];
    __shared__ u16 Bs[2][256 * 40];
    const int tid = threadIdx.x;
    const int wave = tid >> 6, lane = tid & 63;
    const int wr = wave >> 2, wc = wave & 3;
    const int fr = lane & 15, fg = lane >> 4;
    const int bm = blockIdx.x * 128, bn = blockIdx.y * 256;

    const int xr = tid >> 2, xc = (tid & 3) * 8;      // X stage: 128 rows x 32
    const int wrow = tid >> 1, wcol = (tid & 1) * 16; // W stage: 256 rows x 32

    int gr0 = bm + xr; if (gr0 > M - 1) gr0 = M - 1;
    const XT*  xp0 = X + (size_t)gr0 * K + xc;
    const u16* wp0 = W + (size_t)(bn + wrow) * K + wcol;

    f32x4 acc[4][4];
    #pragma unroll
    for (int m = 0; m < 4; ++m)
        #pragma unroll
        for (int n = 0; n < 4; ++n) acc[m][n] = (f32x4){0.f, 0.f, 0.f, 0.f};

    // prologue: stage K-tile 0 into buffer 0
    wlds(&As[0][xr * 40 + xc], loadraw(xp0));
    wlds(&Bs[0][wrow * 40 + wcol],     loadraw(wp0));
    wlds(&Bs[0][wrow * 40 + wcol + 8], loadraw(wp0 + 8));
    __syncthreads();

    const int nk = K >> 5;
    int cur = 0;
    for (int kt = 0; kt < nk; ++kt) {
        const bool nxt = (kt + 1 < nk);
        // issue next tile's global loads into registers (latency hides under MFMA)
        decltype(loadraw(xp0)) xa{};
        bf16x8 wb0{}, wb1{};
        if (nxt) {
            int k0 = (kt + 1) << 5;
            xa  = loadraw(xp0 + k0);
            wb0 = loadraw(wp0 + k0);
            wb1 = loadraw(wp0 + k0 + 8);
        }
        bf16x8 af[4], bg[4];
        #pragma unroll
        for (int m = 0; m < 4; ++m)
            af[m] = *(const bf16x8*)&As[cur][(wr * 64 + m * 16 + fr) * 40 + fg * 8];
        #pragma unroll
        for (int n = 0; n < 4; ++n)
            bg[n] = *(const bf16x8*)&Bs[cur][(wc * 64 + n * 16 + fr) * 40 + fg * 8];
        #pragma unroll
        for (int m = 0; m < 4; ++m)
            #pragma unroll
            for (int n = 0; n < 4; ++n)
                acc[m][n] = mfma_bf16(af[m], bg[n], acc[m][n]);
        if (nxt) {
            wlds(&As[cur ^ 1][xr * 40 + xc], xa);
            wlds(&Bs[cur ^ 1][wrow * 40 + wcol],     wb0);
            wlds(&Bs[cur ^ 1][wrow * 40 + wcol + 8], wb1);
            __syncthreads();
            cur ^= 1;
        }
    }

    #pragma unroll
    for (int m = 0; m < 4; ++m) {
        #pragma unroll
        for (int i = 0; i < 4; ++i) {
            int grow = bm + wr * 64 + m * 16 + fg * 4 + i;
            if (grow >= M) continue;
            #pragma unroll
            for (int n = 0; n < 4; ++n) {
                int gcol = bn + wc * 64 + n * 16 + fr;
                float v = acc[m][n][i] + bias[gcol];
                if (RELU) v = fmaxf(v, 0.f);
                storey(Y + (size_t)grow * N + gcol, v);
            }
        }
    }
}

// ---------------- GEMM v1 (kept for N=128 aw projection) ----------------
__device__ __forceinline__ bf16x8 loadx(const u16* p) { return *(const bf16x8*)p; }
template <typename XT, typename OT, bool RELU>
__global__ __launch_bounds__(256) void k_gemm(
    const XT* __restrict__ X, const u16* __restrict__ W,
    const float* __restrict__ bias, OT* __restrict__ Y,
    int M, int N, int K)
{
    __shared__ u16 Ash[128 * 40];
    __shared__ u16 Bsh[128 * 40];
    const int tid = threadIdx.x;
    const int wave = tid >> 6, lane = tid & 63;
    const int wr = wave >> 1, wc = wave & 1;
    const int fr = lane & 15, fg = lane >> 4;
    const int bm = blockIdx.x * 128, bn = blockIdx.y * 128;
    const int srow = tid >> 2, sc = (tid & 3) * 8;

    f32x4 acc[4][4];
    #pragma unroll
    for (int m = 0; m < 4; ++m)
        #pragma unroll
        for (int n = 0; n < 4; ++n) acc[m][n] = (f32x4){0.f, 0.f, 0.f, 0.f};

    for (int k0 = 0; k0 < K; k0 += 32) {
        __syncthreads();
        #pragma unroll
        for (int i = 0; i < 2; ++i) {
            int row = srow + i * 64;
            int gr = bm + row; if (gr > M - 1) gr = M - 1;
            wlds(&Ash[row * 40 + sc], loadraw(X + (size_t)gr * K + k0 + sc));
            int wn = bn + row; if (wn > N - 1) wn = N - 1;
            wlds(&Bsh[row * 40 + sc], loadraw(W + (size_t)wn * K + k0 + sc));
        }
        __syncthreads();
        bf16x8 af[4], bg[4];
        #pragma unroll
        for (int m = 0; m < 4; ++m)
            af[m] = *(const bf16x8*)&Ash[(wr * 64 + m * 16 + fr) * 40 + fg * 8];
        #pragma unroll
        for (int n = 0; n < 4; ++n)
            bg[n] = *(const bf16x8*)&Bsh[(wc * 64 + n * 16 + fr) * 40 + fg * 8];
        #pragma unroll
        for (int m = 0; m < 4; ++m)
            #pragma unroll
            for (int n = 0; n < 4; ++n)
                acc[m][n] = mfma_bf16(af[m], bg[n], acc[m][n]);
    }

    #pragma unroll
    for (int m = 0; m < 4; ++m) {
        #pragma unroll
        for (int i = 0; i < 4; ++i) {
            int grow = bm + wr * 64 + m * 16 + fg * 4 + i;
            if (grow >= M) continue;
            #pragma unroll
            for (int n = 0; n < 4; ++n) {
                int gcol = bn + wc * 64 + n * 16 + fr;
                if (gcol >= N) continue;
                float v = acc[m][n][i] + bias[gcol];
                if (RELU) v = fmaxf(v, 0.f);
                storey(Y + (size_t)grow * N + gcol, v);
            }
        }
    }
}

// ---------------- flash self-attention v3 (MFMA bf16, KVBLK=128) ----------------
__global__ __launch_bounds__(256) void k_attn(
    const u16* __restrict__ Q, const u16* __restrict__ K,
    const u16* __restrict__ V, u16* __restrict__ O)
{
    __shared__ u16 Ks[128 * 40];       // [key][dh], stride 40
    __shared__ u16 Vt[32 * 136];       // [dh][kv-slot], stride 136 (slot = permuted kv)
    const int b = blockIdx.z, h = blockIdx.y;
    const int q0 = blockIdx.x * 64;
    const int tid = threadIdx.x;
    const int wave = tid >> 6, lane = tid & 63;
    const int fr = lane & 15, fg = lane >> 4;
    constexpr float C2 = 0.25503486f;   // log2(e)/sqrt(32), folded into Q

    int qg = q0 + wave * 16 + fr; if (qg >= LQ_) qg = LQ_ - 1;
    bf16x8 qf;
    {
        bf16x8 qraw = *(const bf16x8*)&Q[((size_t)(b * LQ_ + qg)) * 256 + h * 32 + fg * 8];
        #pragma unroll
        for (int j = 0; j < 8; ++j) qf[j] = (__bf16)((float)qraw[j] * C2);
    }

    const bf16x8 ones = {(__bf16)1.f, (__bf16)1.f, (__bf16)1.f, (__bf16)1.f,
                         (__bf16)1.f, (__bf16)1.f, (__bf16)1.f, (__bf16)1.f};

    f32x4 o0 = (f32x4){0.f,0.f,0.f,0.f}, o1 = (f32x4){0.f,0.f,0.f,0.f};
    f32x4 lacc = (f32x4){0.f,0.f,0.f,0.f};

    const int kr = tid >> 1, kc = (tid & 1) * 16;   // K staging: row, col16
    const int vp = lane, vdh = wave * 8;            // V staging: kv-pair, dh block
    // permuted u32 column for kv-pair vp: cp = (vp5:4, vp2:1, vp3, vp0)
    const int cp = ((vp >> 4) << 4) | (((vp >> 1) & 3) << 2) | (((vp >> 3) & 1) << 1) | (vp & 1);

    for (int kb0 = 0; kb0 < LQ_; kb0 += 128) {
        const bool tail = (kb0 + 128 > LQ_);
        __syncthreads();
        {
            int kg = kb0 + kr; if (kg >= LQ_) kg = LQ_ - 1;
            const u16* kp = &K[((size_t)(b * LQ_ + kg)) * 256 + h * 32 + kc];
            *(bf16x8*)&Ks[kr * 40 + kc]     = *(const bf16x8*)kp;
            *(bf16x8*)&Ks[kr * 40 + kc + 8] = *(const bf16x8*)(kp + 8);
            int v0 = kb0 + 2 * vp, v1 = v0 + 1;
            if (v0 >= LQ_) v0 = LQ_ - 1;
            if (v1 >= LQ_) v1 = LQ_ - 1;
            union { bf16x8 v; u16 s[8]; } va, vb2;
            va.v  = *(const bf16x8*)&V[((size_t)(b * LQ_ + v0)) * 256 + h * 32 + vdh];
            vb2.v = *(const bf16x8*)&V[((size_t)(b * LQ_ + v1)) * 256 + h * 32 + vdh];
            #pragma unroll
            for (int j = 0; j < 8; ++j)
                *(u32*)&Vt[(vdh + j) * 136 + 2 * cp] = (u32)va.s[j] | ((u32)vb2.s[j] << 16);
        }
        __syncthreads();

        // QK + exp: pq[ks] words t=0..3 hold P pairs for kv-pairs (2ks+(t>>1))*8+fg*2+(t&1)
        u32x4 pq[4];
        #pragma unroll
        for (int f = 0; f < 8; ++f) {
            bf16x8 ka = *(const bf16x8*)&Ks[(f * 16 + fr) * 40 + fg * 8];
            f32x4 s = mfma_bf16(ka, qf, (f32x4){0.f,0.f,0.f,0.f});
            if (tail) {
                #pragma unroll
                for (int i = 0; i < 4; ++i)
                    if (kb0 + f * 16 + fg * 4 + i >= LQ_) s[i] = -3e38f;
            }
            float p0 = EXP2(s[0]), p1 = EXP2(s[1]);
            float p2 = EXP2(s[2]), p3 = EXP2(s[3]);
            union { __bf16 h[2]; u32 w; } c0, c1;
            c0.h[0] = (__bf16)p0; c0.h[1] = (__bf16)p1;
            c1.h[0] = (__bf16)p2; c1.h[1] = (__bf16)p3;
            pq[f >> 1][(f & 1) * 2 + 0] = c0.w;
            pq[f >> 1][(f & 1) * 2 + 1] = c1.w;
        }

        // PV + l: O^T(dh,q) += V^T(dh, perm kv) . P^T;  l(q) += sum P
        #pragma unroll
        for (int ks = 0; ks < 4; ++ks) {
            bf16x8 pb  = __builtin_bit_cast(bf16x8, pq[ks]);
            bf16x8 va0 = *(const bf16x8*)&Vt[fr * 136 + ks * 32 + fg * 8];
            bf16x8 va1 = *(const bf16x8*)&Vt[(16 + fr) * 136 + ks * 32 + fg * 8];
            o0 = mfma_bf16(va0, pb, o0);
            o1 = mfma_bf16(va1, pb, o1);
            lacc = mfma_bf16(ones, pb, lacc);
        }
    }

    float inv = 1.f / lacc[0];
    int qout = q0 + wave * 16 + fr;
    if (qout < LQ_) {
        size_t base = ((size_t)(b * LQ_ + qout)) * 256 + h * 32;
        #pragma unroll
        for (int i = 0; i < 4; ++i) {
            O[base + fg * 4 + i]      = f2bf(o0[i] * inv);
            O[base + 16 + fg * 4 + i] = f2bf(o1[i] * inv);
        }
    }
}

// ---------------- residual + LayerNorm ----------------
__device__ __forceinline__ float ldf(const float* p) { return *p; }
__device__ __forceinline__ float ldf(const u16* p)   { return bf2f(*p); }

template <typename RT, typename OT>
__global__ __launch_bounds__(256) void k_resln(
    const u16* __restrict__ X, const RT* __restrict__ R,
    const float* __restrict__ g, const float* __restrict__ bb,
    OT* __restrict__ O)
{
    const int row = blockIdx.x;
    const int d = threadIdx.x;
    const size_t off = (size_t)row * D_ + d;
    float v = ldf(R + off) + bf2f(X[off]);
    __shared__ float r1[4], r2[4];
    int lane = d & 63, wid = d >> 6;
    float s = v;
    #pragma unroll
    for (int o_ = 32; o_ >= 1; o_ >>= 1) s += __shfl_xor(s, o_);
    if (lane == 0) r1[wid] = s;
    __syncthreads();
    float mean = (r1[0] + r1[1] + r1[2] + r1[3]) * (1.f / 256.f);
    float dv = v - mean;
    float sq = dv * dv;
    #pragma unroll
    for (int o_ = 32; o_ >= 1; o_ >>= 1) sq += __shfl_xor(sq, o_);
    if (lane == 0) r2[wid] = sq;
    __syncthreads();
    float var = (r2[0] + r2[1] + r2[2] + r2[3]) * (1.f / 256.f);
    storey(O + off, dv / sqrtf(var + 1e-5f) * g[d] + bb[d]);
}

// ---------------- deformable sampling (two-phase, LDS precompute) ----------------
__global__ __launch_bounds__(256) void k_sample(
    const float* __restrict__ offs, const float* __restrict__ aw,
    const u16* __restrict__ value, const float* __restrict__ refp,
    u16* __restrict__ acc_out)
{
    __shared__ u32 pts[2][128][8];   // [qsub][lp*8+h][0..3 off, 4..7 w]
    const int t = threadIdx.x;
    const int bq0 = blockIdx.x * 2;          // 2 queries, same batch (LQ even)
    const int b = bq0 / LQ_;

    constexpr int Hl[4] = {100, 50, 25, 13};
    constexpr int Wl[4] = {150, 75, 38, 19};
    constexpr int LS[4] = {0, 15000, 18750, 19700};

    // ---- phase 1 ----
    {
        const int qsub = t >> 7;
        const int pt = t & 127;
        const int h = pt >> 4, lp = pt & 15;
        const int l = lp >> 2, p = lp & 3;
        const int bq = bq0 + qsub;

        float2 oxy = *(const float2*)&offs[(size_t)bq * 256 + h * 32 + l * 8 + p * 2];
        float av = aw[(size_t)bq * 128 + h * 16 + lp];
        float mx = av;
        #pragma unroll
        for (int s = 1; s < 16; s <<= 1) mx = fmaxf(mx, __shfl_xor(mx, s));
        float e = __expf(av - mx);
        float sum = e;
        #pragma unroll
        for (int s = 1; s < 16; s <<= 1) sum += __shfl_xor(sum, s);
        float a = e / sum;

        float2 rxy = *(const float2*)&refp[(size_t)bq * 8 + l * 2];
        const float Wf = (float)Wl[l], Hf = (float)Hl[l];
        float x = (rxy.x + oxy.x / Wf) * Wf - 0.5f;
        float y = (rxy.y + oxy.y / Hf) * Hf - 0.5f;
        float x0f = floorf(x), y0f = floorf(y);
        int x0 = (int)x0f, y0 = (int)y0f;
        float wx1 = x - x0f, wy1 = y - y0f;
        float wx0 = 1.f - wx1, wy0 = 1.f - wy1;

        u32 ov[4]; float wv[4];
        #pragma unroll
        for (int c = 0; c < 4; ++c) {
            int cy = c >> 1, cx = c & 1;
            int yi = y0 + cy, xi = x0 + cx;
            bool valid = (yi >= 0) && (yi < Hl[l]) && (xi >= 0) && (xi < Wl[l]);
            ov[c] = valid ? (u32)((LS[l] + yi * Wl[l] + xi) * 256 + h * 32) : 0u;
            float w = (cy ? wy1 : wy0) * (cx ? wx1 : wx0) * a;
            wv[c] = valid ? w : 0.f;
        }
        u32* dst = pts[qsub][lp * 8 + h];
        *(uint4*)dst = make_uint4(ov[0], ov[1], ov[2], ov[3]);
        float4 wq = make_float4(wv[0], wv[1], wv[2], wv[3]);
        *(float4*)(dst + 4) = wq;
    }
    __syncthreads();

    // ---- phase 2 ----
    const int qsub = t >> 7;
    const int h = (t >> 4) & 7;
    const int dp = t & 15;                    // dh pair: dh = 2*dp, 2*dp+1
    const u16* vb = value + (size_t)b * LIN_ * 256 + 2 * dp;
    float a0 = 0.f, a1 = 0.f;
    #pragma unroll
    for (int i = 0; i < 16; ++i) {
        const u32* P = pts[qsub][i * 8 + h];
        uint4 o4 = *(const uint4*)P;
        float4 w4 = *(const float4*)(P + 4);
        u32 g;
        g = *(const u32*)&vb[o4.x]; a0 += w4.x * bf2f((u16)g); a1 += w4.x * bf2f((u16)(g >> 16));
        g = *(const u32*)&vb[o4.y]; a0 += w4.y * bf2f((u16)g); a1 += w4.y * bf2f((u16)(g >> 16));
        g = *(const u32*)&vb[o4.z]; a0 += w4.z * bf2f((u16)g); a1 += w4.z * bf2f((u16)(g >> 16));
        g = *(const u32*)&vb[o4.w]; a0 += w4.w * bf2f((u16)g); a1 += w4.w * bf2f((u16)(g >> 16));
    }
    const int bq = bq0 + qsub;
    u32 packed = (u32)f2bf(a0) | ((u32)f2bf(a1) << 16);
    *(u32*)&acc_out[(size_t)bq * 256 + h * 32 + 2 * dp] = packed;
}

// ---------------- launch ----------------
extern "C" void kernel_launch(void* const* d_in, const int* in_sizes, int n_in,
                              void* d_out, int out_size, void* d_ws, size_t ws_size,
                              hipStream_t stream)
{
    (void)in_sizes; (void)n_in; (void)out_size; (void)ws_size;
    const float* tgt   = (const float*)d_in[0];
    const float* qpos  = (const float*)d_in[1];
    const float* refp  = (const float*)d_in[2];
    const float* src   = (const float*)d_in[3];
    const float* qW    = (const float*)d_in[4];
    const float* qb    = (const float*)d_in[5];
    const float* kW    = (const float*)d_in[6];
    const float* kb    = (const float*)d_in[7];
    const float* vW    = (const float*)d_in[8];
    const float* vb    = (const float*)d_in[9];
    const float* oW    = (const float*)d_in[10];
    const float* ob    = (const float*)d_in[11];
    const float* a_q   = (const float*)d_in[12];
    const float* a_k   = (const float*)d_in[13];
    const float* a_v   = (const float*)d_in[14];
    const float* a_o   = (const float*)d_in[15];
    const float* val_W = (const float*)d_in[16];
    const float* val_b = (const float*)d_in[17];
    const float* a_val = (const float*)d_in[18];
    const float* off_W = (const float*)d_in[19];
    const float* off_b = (const float*)d_in[20];
    const float* aw_W  = (const float*)d_in[21];
    const float* aw_b  = (const float*)d_in[22];
    const float* out_W = (const float*)d_in[23];
    const float* out_b = (const float*)d_in[24];
    const float* a_out = (const float*)d_in[25];
    const float* W1    = (const float*)d_in[26];
    const float* b1    = (const float*)d_in[27];
    const float* a_w1  = (const float*)d_in[28];
    const float* W2    = (const float*)d_in[29];
    const float* b2    = (const float*)d_in[30];
    const float* a_w2  = (const float*)d_in[31];
    const float* ln1_g = (const float*)d_in[32];
    const float* ln1_b = (const float*)d_in[33];
    const float* ln2_g = (const float*)d_in[34];
    const float* ln2_b = (const float*)d_in[35];
    const float* ln3_g = (const float*)d_in[36];
    const float* ln3_b = (const float*)d_in[37];

    // ---- workspace layout ----
    u16* wq_q  = (u16*)d_ws;
    u16* wq_k  = wq_q + 65536;
    u16* wq_v  = wq_k + 65536;
    u16* wq_o  = wq_v + 65536;
    u16* wq_vl = wq_o + 65536;
    u16* wq_ot = wq_vl + 65536;
    u16* w_off = wq_ot + 65536;
    u16* w_aw  = w_off + 65536;
    u16* wq_1  = w_aw + 32768;
    u16* wq_2  = wq_1 + 262144;
    u16* bufA  = wq_2 + 262144;      // NELEM bf16 each
    u16* bufB  = bufA + NELEM_;
    u16* bufC  = bufB + NELEM_;
    u16* bufD  = bufC + NELEM_;
    u16* bufE  = bufD + NELEM_;
    float* offs = (float*)(bufE + NELEM_);   // NELEM f32
    float* awb  = offs + NELEM_;             // MQ*128 f32
    u16* valb   = (u16*)(awb + MQ_ * 128);   // B*LIN*256 bf16 (later reused as ffn1)

    const int TB = 256;
    const int MVAL = B_ * LIN_;
    const int GX = CDIV(MQ_, 128);           // 113

    // weights
    k_quant<<<CDIV(65536, TB), TB, 0, stream>>>(qW, a_q, wq_q, 65536);
    k_quant<<<CDIV(65536, TB), TB, 0, stream>>>(kW, a_k, wq_k, 65536);
    k_quant<<<CDIV(65536, TB), TB, 0, stream>>>(vW, a_v, wq_v, 65536);
    k_quant<<<CDIV(65536, TB), TB, 0, stream>>>(oW, a_o, wq_o, 65536);
    k_quant<<<CDIV(65536, TB), TB, 0, stream>>>(val_W, a_val, wq_vl, 65536);
    k_quant<<<CDIV(65536, TB), TB, 0, stream>>>(out_W, a_out, wq_ot, 65536);
    k_quant<<<CDIV(262144, TB), TB, 0, stream>>>(W1, a_w1, wq_1, 262144);
    k_quant<<<CDIV(262144, TB), TB, 0, stream>>>(W2, a_w2, wq_2, 262144);
    k_cvt<<<CDIV(65536, TB), TB, 0, stream>>>(off_W, w_off, 65536);
    k_cvt<<<CDIV(32768, TB), TB, 0, stream>>>(aw_W, w_aw, 32768);

    // activation prep
    k_addcvt<<<CDIV(NELEM_, TB), TB, 0, stream>>>(tgt, qpos, bufA, NELEM_);  // qk_in
    k_cvt<<<CDIV(NELEM_, TB), TB, 0, stream>>>(tgt, bufB, NELEM_);           // tgt_bf

    // ---- self-attention ----
    k_gemm2<u16, u16, false><<<dim3(GX, 1), 512, 0, stream>>>(bufA, wq_q, qb, bufC, MQ_, 256, 256);
    k_gemm2<u16, u16, false><<<dim3(GX, 1), 512, 0, stream>>>(bufA, wq_k, kb, bufD, MQ_, 256, 256);
    k_gemm2<u16, u16, false><<<dim3(GX, 1), 512, 0, stream>>>(bufB, wq_v, vb, bufE, MQ_, 256, 256);
    k_attn<<<dim3(CDIV(LQ_,64), H_, B_), TB, 0, stream>>>(bufC, bufD, bufE, bufA);       // sa -> A
    k_gemm2<u16, u16, false><<<dim3(GX, 1), 512, 0, stream>>>(bufA, wq_o, ob, bufB, MQ_, 256, 256);
    k_resln<float, u16><<<MQ_, TB, 0, stream>>>(bufB, tgt, ln2_g, ln2_b, bufC);          // tgt2 -> C

    // ---- deformable cross-attention ----
    k_addcvt2<<<CDIV(NELEM_, TB), TB, 0, stream>>>(bufC, qpos, bufD, NELEM_);            // query -> D
    k_gemm2<float, u16, false><<<dim3(CDIV(MVAL,128), 1), 512, 0, stream>>>(src, wq_vl, val_b, valb, MVAL, 256, 256);
    k_gemm2<u16, float, false><<<dim3(GX, 1), 512, 0, stream>>>(bufD, w_off, off_b, offs, MQ_, 256, 256);
    k_gemm<u16, float, false><<<dim3(GX, 1), TB, 0, stream>>>(bufD, w_aw, aw_b, awb, MQ_, 128, 256);
    k_sample<<<MQ_ / 2, TB, 0, stream>>>(offs, awb, valb, refp, bufE);                   // acc -> E
    k_gemm2<u16, u16, false><<<dim3(GX, 1), 512, 0, stream>>>(bufE, wq_ot, out_b, bufA, MQ_, 256, 256);
    k_resln<u16, u16><<<MQ_, TB, 0, stream>>>(bufA, bufC, ln1_g, ln1_b, bufB);           // tgt3 -> B

    // ---- FFN ----
    u16* ffn1 = valb;  // value dead after k_sample
    k_gemm2<u16, u16, true ><<<dim3(GX, 4), 512, 0, stream>>>(bufB, wq_1, b1, ffn1, MQ_, 1024, 256);
    k_gemm2<u16, u16, false><<<dim3(GX, 1), 512, 0, stream>>>(ffn1, wq_2, b2, bufD, MQ_, 256, 1024);
    k_resln<u16, float><<<MQ_, TB, 0, stream>>>(bufD, bufB, ln3_g, ln3_b, (float*)d_out);
}

// Round 7
// 385.309 us; speedup vs baseline: 4.6395x; 1.0344x over previous
//
#include <hip/hip_runtime.h>
#include <hip/hip_bf16.h>

// ---------------- constants ----------------
static constexpr int B_   = 8;
static constexpr int LQ_  = 1800;
static constexpr int D_   = 256;
static constexpr int H_   = 8;
static constexpr int DFF_ = 1024;
static constexpr int LIN_ = 19947;
static constexpr int MQ_  = B_ * LQ_;       // 14400
static constexpr int NELEM_ = MQ_ * D_;     // 3,686,400

#define CDIV(a, b) (((a) + (b) - 1) / (b))

typedef unsigned short u16;
typedef unsigned int   u32;
typedef unsigned long long u64;
typedef __attribute__((ext_vector_type(8))) __bf16 bf16x8;
typedef __attribute__((ext_vector_type(4))) float  f32x4;
typedef __attribute__((ext_vector_type(4))) u32    u32x4;

#if __has_builtin(__builtin_amdgcn_exp2f)
#define EXP2(x) __builtin_amdgcn_exp2f(x)
#else
#define EXP2(x) exp2f(x)
#endif

// ---------------- bf16 helpers (RNE via native cast -> v_cvt_pk_bf16_f32) ----
__device__ __forceinline__ u16 f2bf(float f) {
    union { __bf16 h; u16 u; } v; v.h = (__bf16)f; return v.u;
}
__device__ __forceinline__ float bf2f(u16 u) {
    union { u32 u; float f; } v; v.u = ((u32)u) << 16;
    return v.f;
}

__device__ __forceinline__ f32x4 mfma_bf16(bf16x8 a, bf16x8 b, f32x4 c) {
    return __builtin_amdgcn_mfma_f32_16x16x32_bf16(a, b, c, 0, 0, 0);
}

// async global->LDS, 16B per lane, LDS dest = wave-uniform base + lane*16
__device__ __forceinline__ void gload16(const void* g, void* l) {
    __builtin_amdgcn_global_load_lds(
        (const __attribute__((address_space(1))) void*)g,
        (__attribute__((address_space(3))) void*)l,
        16, 0, 0);
}

// ---------------- small elementwise kernels ----------------
__global__ void k_quant(const float* __restrict__ w, const float* __restrict__ alpha,
                        u16* __restrict__ o, int n) {
    int i = blockIdx.x * blockDim.x + threadIdx.x;
    if (i >= n) return;
    float a = alpha[0];
    float wn = fminf(fmaxf(w[i] / a, -8.f), 7.f);
    o[i] = f2bf(rintf(wn) * a);
}

__global__ void k_cvt(const float* __restrict__ w, u16* __restrict__ o, int n) {
    int i = blockIdx.x * blockDim.x + threadIdx.x;
    if (i < n) o[i] = f2bf(w[i]);
}

__global__ void k_addcvt(const float* __restrict__ a, const float* __restrict__ b,
                         u16* __restrict__ o, int n) {
    int i = blockIdx.x * blockDim.x + threadIdx.x;
    if (i < n) o[i] = f2bf(a[i] + b[i]);
}

__global__ void k_addcvt2(const u16* __restrict__ a, const float* __restrict__ b,
                          u16* __restrict__ o, int n) {
    int i = blockIdx.x * blockDim.x + threadIdx.x;
    if (i < n) o[i] = f2bf(bf2f(a[i]) + b[i]);
}

// ---------------- staging-load helpers (k_gemm v1 only) ----------------
struct rawf8 { float4 a, b; };
__device__ __forceinline__ bf16x8 loadraw(const u16* p) { return *(const bf16x8*)p; }
__device__ __forceinline__ rawf8  loadraw(const float* p) {
    rawf8 r; r.a = *(const float4*)p; r.b = *(const float4*)(p + 4); return r;
}
__device__ __forceinline__ void wlds(u16* d, bf16x8 v) { *(bf16x8*)d = v; }
__device__ __forceinline__ void wlds(u16* d, rawf8 v) {
    bf16x8 r;
    r[0] = (__bf16)v.a.x; r[1] = (__bf16)v.a.y; r[2] = (__bf16)v.a.z; r[3] = (__bf16)v.a.w;
    r[4] = (__bf16)v.b.x; r[5] = (__bf16)v.b.y; r[6] = (__bf16)v.b.z; r[7] = (__bf16)v.b.w;
    *(bf16x8*)d = r;
}
__device__ __forceinline__ void storey(float* p, float v) { *p = v; }
__device__ __forceinline__ void storey(u16* p, float v)   { *p = f2bf(v); }

// ---------------- GEMM v3: Y = X @ W^T + bias ----------------------------
// 64xBN tile, 256 thr = 4 waves (2x2), wave tile 32x(BN/2).
// global_load_lds width-16 staging into LINEAR LDS; bank conflicts fixed by
// XOR slot swizzle applied to the per-lane GLOBAL source address (stage) and
// to the ds_read address (frag load) -- same involution both sides.
// X dtype: u16 (bf16) staged directly; f32 staged raw, converted at frag read.
template <typename XT, typename OT, bool RELU, int BN>
__global__ __launch_bounds__(256) void k_gemm3(
    const XT* __restrict__ X, const u16* __restrict__ W,
    const float* __restrict__ bias, OT* __restrict__ Y,
    int M, int N, int K)
{
    constexpr int WN  = BN / 2;          // wave col span
    constexpr int NFR = WN / 16;         // B frags per wave
    constexpr bool XF32 = (sizeof(XT) == 4);
    constexpr int ASZ = 64 * 32 * (XF32 ? 2 : 1);   // u16 units
    constexpr int BSZ = BN * 32;
    __shared__ __align__(16) u16 As[2][ASZ];
    __shared__ __align__(16) u16 Bs[2][BSZ];

    const int tid = threadIdx.x;
    const int wave = tid >> 6, lane = tid & 63;
    const int wr = wave >> 1, wc = wave & 1;
    const int fr = lane & 15, fg = lane >> 4;
    const int bm = blockIdx.x * 64, bn = blockIdx.y * BN;

    f32x4 acc[2][NFR];
    #pragma unroll
    for (int m = 0; m < 2; ++m)
        #pragma unroll
        for (int n = 0; n < NFR; ++n) acc[m][n] = (f32x4){0.f, 0.f, 0.f, 0.f};

    auto stageA = [&](int buf, int kt) {
        if constexpr (!XF32) {
            // 64x32 bf16 = 4KB = 1 op; wave w covers rows [w*16, w*16+16)
            int r = (wave << 4) + (lane >> 2);
            int grow = bm + r; if (grow > M - 1) grow = M - 1;
            int cs = (lane & 3) ^ ((lane >> 3) & 3);        // slot ^ ((r>>1)&3)
            gload16((const u16*)X + (size_t)grow * K + (kt << 5) + (cs << 3),
                    &As[buf][wave * 512]);
        } else {
            // 64x32 f32 = 8KB = 2 ops; op t: wave w covers rows [t*32+w*8, +8)
            float* Af = (float*)As[buf];
            #pragma unroll
            for (int t = 0; t < 2; ++t) {
                int r = (t << 5) + (wave << 3) + (lane >> 3);
                int grow = bm + r; if (grow > M - 1) grow = M - 1;
                int cs = (lane & 7) ^ ((lane >> 3) & 7);    // slot ^ (r&7)
                gload16((const float*)X + (size_t)grow * K + (kt << 5) + (cs << 2),
                        &Af[((t << 5) + (wave << 3)) * 32]);
            }
        }
    };
    auto stageB = [&](int buf, int kt) {
        #pragma unroll
        for (int t = 0; t < BN / 64; ++t) {
            int r = (t << 6) + (wave << 4) + (lane >> 2);
            int cs = (lane & 3) ^ ((lane >> 3) & 3);
            gload16(W + (size_t)(bn + r) * K + (kt << 5) + (cs << 3),
                    &Bs[buf][((t << 6) + (wave << 4)) * 32]);
        }
    };

    stageA(0, 0); stageB(0, 0);
    __syncthreads();

    const int nk = K >> 5;
    int cur = 0;
    for (int kt = 0; kt < nk; ++kt) {
        if (kt + 1 < nk) { stageA(cur ^ 1, kt + 1); stageB(cur ^ 1, kt + 1); }

        bf16x8 af[2], bg[NFR];
        #pragma unroll
        for (int m = 0; m < 2; ++m) {
            int r = wr * 32 + m * 16 + fr;
            if constexpr (!XF32) {
                af[m] = *(const bf16x8*)&As[cur][r * 32 + ((fg ^ ((fr >> 1) & 3)) << 3)];
            } else {
                const float* Af = (const float*)As[cur];
                int s0 = (fg << 1) ^ (fr & 7);
                f32x4 x0 = *(const f32x4*)&Af[r * 32 + (s0 << 2)];
                f32x4 x1 = *(const f32x4*)&Af[r * 32 + ((s0 ^ 1) << 2)];
                #pragma unroll
                for (int j = 0; j < 4; ++j) {
                    af[m][j]     = (__bf16)x0[j];
                    af[m][4 + j] = (__bf16)x1[j];
                }
            }
        }
        #pragma unroll
        for (int n = 0; n < NFR; ++n) {
            int r = wc * WN + n * 16 + fr;
            bg[n] = *(const bf16x8*)&Bs[cur][r * 32 + ((fg ^ ((fr >> 1) & 3)) << 3)];
        }
        #pragma unroll
        for (int m = 0; m < 2; ++m)
            #pragma unroll
            for (int n = 0; n < NFR; ++n)
                acc[m][n] = mfma_bf16(af[m], bg[n], acc[m][n]);

        __syncthreads();   // drains staging vmcnt + frag lgkmcnt (m97 structure)
        cur ^= 1;
    }

    #pragma unroll
    for (int m = 0; m < 2; ++m) {
        #pragma unroll
        for (int i = 0; i < 4; ++i) {
            int grow = bm + wr * 32 + m * 16 + fg * 4 + i;
            if (grow >= M) continue;
            #pragma unroll
            for (int n = 0; n < NFR; ++n) {
                int gcol = bn + wc * WN + n * 16 + fr;
                float v = acc[m][n][i] + bias[gcol];
                if (RELU) v = fmaxf(v, 0.f);
                storey(Y + (size_t)grow * N + gcol, v);
            }
        }
    }
}

// ---------------- GEMM v1 (kept for N=128 aw projection) ----------------
template <typename XT, typename OT, bool RELU>
__global__ __launch_bounds__(256) void k_gemm(
    const XT* __restrict__ X, const u16* __restrict__ W,
    const float* __restrict__ bias, OT* __restrict__ Y,
    int M, int N, int K)
{
    __shared__ u16 Ash[128 * 40];
    __shared__ u16 Bsh[128 * 40];
    const int tid = threadIdx.x;
    const int wave = tid >> 6, lane = tid & 63;
    const int wr = wave >> 1, wc = wave & 1;
    const int fr = lane & 15, fg = lane >> 4;
    const int bm = blockIdx.x * 128, bn = blockIdx.y * 128;
    const int srow = tid >> 2, sc = (tid & 3) * 8;

    f32x4 acc[4][4];
    #pragma unroll
    for (int m = 0; m < 4; ++m)
        #pragma unroll
        for (int n = 0; n < 4; ++n) acc[m][n] = (f32x4){0.f, 0.f, 0.f, 0.f};

    for (int k0 = 0; k0 < K; k0 += 32) {
        __syncthreads();
        #pragma unroll
        for (int i = 0; i < 2; ++i) {
            int row = srow + i * 64;
            int gr = bm + row; if (gr > M - 1) gr = M - 1;
            wlds(&Ash[row * 40 + sc], loadraw(X + (size_t)gr * K + k0 + sc));
            int wn = bn + row; if (wn > N - 1) wn = N - 1;
            wlds(&Bsh[row * 40 + sc], loadraw(W + (size_t)wn * K + k0 + sc));
        }
        __syncthreads();
        bf16x8 af[4], bg[4];
        #pragma unroll
        for (int m = 0; m < 4; ++m)
            af[m] = *(const bf16x8*)&Ash[(wr * 64 + m * 16 + fr) * 40 + fg * 8];
        #pragma unroll
        for (int n = 0; n < 4; ++n)
            bg[n] = *(const bf16x8*)&Bsh[(wc * 64 + n * 16 + fr) * 40 + fg * 8];
        #pragma unroll
        for (int m = 0; m < 4; ++m)
            #pragma unroll
            for (int n = 0; n < 4; ++n)
                acc[m][n] = mfma_bf16(af[m], bg[n], acc[m][n]);
    }

    #pragma unroll
    for (int m = 0; m < 4; ++m) {
        #pragma unroll
        for (int i = 0; i < 4; ++i) {
            int grow = bm + wr * 64 + m * 16 + fg * 4 + i;
            if (grow >= M) continue;
            #pragma unroll
            for (int n = 0; n < 4; ++n) {
                int gcol = bn + wc * 64 + n * 16 + fr;
                if (gcol >= N) continue;
                float v = acc[m][n][i] + bias[gcol];
                if (RELU) v = fmaxf(v, 0.f);
                storey(Y + (size_t)grow * N + gcol, v);
            }
        }
    }
}

// ---------------- flash self-attention v3 (MFMA bf16, KVBLK=128) ----------------
__global__ __launch_bounds__(256) void k_attn(
    const u16* __restrict__ Q, const u16* __restrict__ K,
    const u16* __restrict__ V, u16* __restrict__ O)
{
    __shared__ u16 Ks[128 * 40];       // [key][dh], stride 40
    __shared__ u16 Vt[32 * 136];       // [dh][kv-slot], stride 136 (slot = permuted kv)
    const int b = blockIdx.z, h = blockIdx.y;
    const int q0 = blockIdx.x * 64;
    const int tid = threadIdx.x;
    const int wave = tid >> 6, lane = tid & 63;
    const int fr = lane & 15, fg = lane >> 4;
    constexpr float C2 = 0.25503486f;   // log2(e)/sqrt(32), folded into Q

    int qg = q0 + wave * 16 + fr; if (qg >= LQ_) qg = LQ_ - 1;
    bf16x8 qf;
    {
        bf16x8 qraw = *(const bf16x8*)&Q[((size_t)(b * LQ_ + qg)) * 256 + h * 32 + fg * 8];
        #pragma unroll
        for (int j = 0; j < 8; ++j) qf[j] = (__bf16)((float)qraw[j] * C2);
    }

    const bf16x8 ones = {(__bf16)1.f, (__bf16)1.f, (__bf16)1.f, (__bf16)1.f,
                         (__bf16)1.f, (__bf16)1.f, (__bf16)1.f, (__bf16)1.f};

    f32x4 o0 = (f32x4){0.f,0.f,0.f,0.f}, o1 = (f32x4){0.f,0.f,0.f,0.f};
    f32x4 lacc = (f32x4){0.f,0.f,0.f,0.f};

    const int kr = tid >> 1, kc = (tid & 1) * 16;   // K staging: row, col16
    const int vp = lane, vdh = wave * 8;            // V staging: kv-pair, dh block
    const int cp = ((vp >> 4) << 4) | (((vp >> 1) & 3) << 2) | (((vp >> 3) & 1) << 1) | (vp & 1);

    for (int kb0 = 0; kb0 < LQ_; kb0 += 128) {
        const bool tail = (kb0 + 128 > LQ_);
        __syncthreads();
        {
            int kg = kb0 + kr; if (kg >= LQ_) kg = LQ_ - 1;
            const u16* kp = &K[((size_t)(b * LQ_ + kg)) * 256 + h * 32 + kc];
            *(bf16x8*)&Ks[kr * 40 + kc]     = *(const bf16x8*)kp;
            *(bf16x8*)&Ks[kr * 40 + kc + 8] = *(const bf16x8*)(kp + 8);
            int v0 = kb0 + 2 * vp, v1 = v0 + 1;
            if (v0 >= LQ_) v0 = LQ_ - 1;
            if (v1 >= LQ_) v1 = LQ_ - 1;
            union { bf16x8 v; u16 s[8]; } va, vb2;
            va.v  = *(const bf16x8*)&V[((size_t)(b * LQ_ + v0)) * 256 + h * 32 + vdh];
            vb2.v = *(const bf16x8*)&V[((size_t)(b * LQ_ + v1)) * 256 + h * 32 + vdh];
            #pragma unroll
            for (int j = 0; j < 8; ++j)
                *(u32*)&Vt[(vdh + j) * 136 + 2 * cp] = (u32)va.s[j] | ((u32)vb2.s[j] << 16);
        }
        __syncthreads();

        u32x4 pq[4];
        #pragma unroll
        for (int f = 0; f < 8; ++f) {
            bf16x8 ka = *(const bf16x8*)&Ks[(f * 16 + fr) * 40 + fg * 8];
            f32x4 s = mfma_bf16(ka, qf, (f32x4){0.f,0.f,0.f,0.f});
            if (tail) {
                #pragma unroll
                for (int i = 0; i < 4; ++i)
                    if (kb0 + f * 16 + fg * 4 + i >= LQ_) s[i] = -3e38f;
            }
            float p0 = EXP2(s[0]), p1 = EXP2(s[1]);
            float p2 = EXP2(s[2]), p3 = EXP2(s[3]);
            union { __bf16 h[2]; u32 w; } c0, c1;
            c0.h[0] = (__bf16)p0; c0.h[1] = (__bf16)p1;
            c1.h[0] = (__bf16)p2; c1.h[1] = (__bf16)p3;
            pq[f >> 1][(f & 1) * 2 + 0] = c0.w;
            pq[f >> 1][(f & 1) * 2 + 1] = c1.w;
        }

        #pragma unroll
        for (int ks = 0; ks < 4; ++ks) {
            bf16x8 pb  = __builtin_bit_cast(bf16x8, pq[ks]);
            bf16x8 va0 = *(const bf16x8*)&Vt[fr * 136 + ks * 32 + fg * 8];
            bf16x8 va1 = *(const bf16x8*)&Vt[(16 + fr) * 136 + ks * 32 + fg * 8];
            o0 = mfma_bf16(va0, pb, o0);
            o1 = mfma_bf16(va1, pb, o1);
            lacc = mfma_bf16(ones, pb, lacc);
        }
    }

    float inv = 1.f / lacc[0];
    int qout = q0 + wave * 16 + fr;
    if (qout < LQ_) {
        size_t base = ((size_t)(b * LQ_ + qout)) * 256 + h * 32;
        #pragma unroll
        for (int i = 0; i < 4; ++i) {
            O[base + fg * 4 + i]      = f2bf(o0[i] * inv);
            O[base + 16 + fg * 4 + i] = f2bf(o1[i] * inv);
        }
    }
}

// ---------------- residual + LayerNorm ----------------
__device__ __forceinline__ float ldf(const float* p) { return *p; }
__device__ __forceinline__ float ldf(const u16* p)   { return bf2f(*p); }

template <typename RT, typename OT>
__global__ __launch_bounds__(256) void k_resln(
    const u16* __restrict__ X, const RT* __restrict__ R,
    const float* __restrict__ g, const float* __restrict__ bb,
    OT* __restrict__ O)
{
    const int row = blockIdx.x;
    const int d = threadIdx.x;
    const size_t off = (size_t)row * D_ + d;
    float v = ldf(R + off) + bf2f(X[off]);
    __shared__ float r1[4], r2[4];
    int lane = d & 63, wid = d >> 6;
    float s = v;
    #pragma unroll
    for (int o_ = 32; o_ >= 1; o_ >>= 1) s += __shfl_xor(s, o_);
    if (lane == 0) r1[wid] = s;
    __syncthreads();
    float mean = (r1[0] + r1[1] + r1[2] + r1[3]) * (1.f / 256.f);
    float dv = v - mean;
    float sq = dv * dv;
    #pragma unroll
    for (int o_ = 32; o_ >= 1; o_ >>= 1) sq += __shfl_xor(sq, o_);
    if (lane == 0) r2[wid] = sq;
    __syncthreads();
    float var = (r2[0] + r2[1] + r2[2] + r2[3]) * (1.f / 256.f);
    storey(O + off, dv / sqrtf(var + 1e-5f) * g[d] + bb[d]);
}

// ---------------- deformable sampling (two-phase, LDS precompute) ----------------
__global__ __launch_bounds__(256) void k_sample(
    const float* __restrict__ offs, const float* __restrict__ aw,
    const u16* __restrict__ value, const float* __restrict__ refp,
    u16* __restrict__ acc_out)
{
    __shared__ u32 pts[2][128][8];   // [qsub][lp*8+h][0..3 off, 4..7 w]
    const int t = threadIdx.x;
    const int bq0 = blockIdx.x * 2;          // 2 queries, same batch (LQ even)
    const int b = bq0 / LQ_;

    constexpr int Hl[4] = {100, 50, 25, 13};
    constexpr int Wl[4] = {150, 75, 38, 19};
    constexpr int LS[4] = {0, 15000, 18750, 19700};

    // ---- phase 1 ----
    {
        const int qsub = t >> 7;
        const int pt = t & 127;
        const int h = pt >> 4, lp = pt & 15;
        const int l = lp >> 2, p = lp & 3;
        const int bq = bq0 + qsub;

        float2 oxy = *(const float2*)&offs[(size_t)bq * 256 + h * 32 + l * 8 + p * 2];
        float av = aw[(size_t)bq * 128 + h * 16 + lp];
        float mx = av;
        #pragma unroll
        for (int s = 1; s < 16; s <<= 1) mx = fmaxf(mx, __shfl_xor(mx, s));
        float e = __expf(av - mx);
        float sum = e;
        #pragma unroll
        for (int s = 1; s < 16; s <<= 1) sum += __shfl_xor(sum, s);
        float a = e / sum;

        float2 rxy = *(const float2*)&refp[(size_t)bq * 8 + l * 2];
        const float Wf = (float)Wl[l], Hf = (float)Hl[l];
        float x = (rxy.x + oxy.x / Wf) * Wf - 0.5f;
        float y = (rxy.y + oxy.y / Hf) * Hf - 0.5f;
        float x0f = floorf(x), y0f = floorf(y);
        int x0 = (int)x0f, y0 = (int)y0f;
        float wx1 = x - x0f, wy1 = y - y0f;
        float wx0 = 1.f - wx1, wy0 = 1.f - wy1;

        u32 ov[4]; float wv[4];
        #pragma unroll
        for (int c = 0; c < 4; ++c) {
            int cy = c >> 1, cx = c & 1;
            int yi = y0 + cy, xi = x0 + cx;
            bool valid = (yi >= 0) && (yi < Hl[l]) && (xi >= 0) && (xi < Wl[l]);
            ov[c] = valid ? (u32)((LS[l] + yi * Wl[l] + xi) * 256 + h * 32) : 0u;
            float w = (cy ? wy1 : wy0) * (cx ? wx1 : wx0) * a;
            wv[c] = valid ? w : 0.f;
        }
        u32* dst = pts[qsub][lp * 8 + h];
        *(uint4*)dst = make_uint4(ov[0], ov[1], ov[2], ov[3]);
        float4 wq = make_float4(wv[0], wv[1], wv[2], wv[3]);
        *(float4*)(dst + 4) = wq;
    }
    __syncthreads();

    // ---- phase 2 ----
    const int qsub = t >> 7;
    const int h = (t >> 4) & 7;
    const int dp = t & 15;                    // dh pair: dh = 2*dp, 2*dp+1
    const u16* vb = value + (size_t)b * LIN_ * 256 + 2 * dp;
    float a0 = 0.f, a1 = 0.f;
    #pragma unroll
    for (int i = 0; i < 16; ++i) {
        const u32* P = pts[qsub][i * 8 + h];
        uint4 o4 = *(const uint4*)P;
        float4 w4 = *(const float4*)(P + 4);
        u32 g;
        g = *(const u32*)&vb[o4.x]; a0 += w4.x * bf2f((u16)g); a1 += w4.x * bf2f((u16)(g >> 16));
        g = *(const u32*)&vb[o4.y]; a0 += w4.y * bf2f((u16)g); a1 += w4.y * bf2f((u16)(g >> 16));
        g = *(const u32*)&vb[o4.z]; a0 += w4.z * bf2f((u16)g); a1 += w4.z * bf2f((u16)(g >> 16));
        g = *(const u32*)&vb[o4.w]; a0 += w4.w * bf2f((u16)g); a1 += w4.w * bf2f((u16)(g >> 16));
    }
    const int bq = bq0 + qsub;
    u32 packed = (u32)f2bf(a0) | ((u32)f2bf(a1) << 16);
    *(u32*)&acc_out[(size_t)bq * 256 + h * 32 + 2 * dp] = packed;
}

// ---------------- launch ----------------
extern "C" void kernel_launch(void* const* d_in, const int* in_sizes, int n_in,
                              void* d_out, int out_size, void* d_ws, size_t ws_size,
                              hipStream_t stream)
{
    (void)in_sizes; (void)n_in; (void)out_size; (void)ws_size;
    const float* tgt   = (const float*)d_in[0];
    const float* qpos  = (const float*)d_in[1];
    const float* refp  = (const float*)d_in[2];
    const float* src   = (const float*)d_in[3];
    const float* qW    = (const float*)d_in[4];
    const float* qb    = (const float*)d_in[5];
    const float* kW    = (const float*)d_in[6];
    const float* kb    = (const float*)d_in[7];
    const float* vW    = (const float*)d_in[8];
    const float* vb    = (const float*)d_in[9];
    const float* oW    = (const float*)d_in[10];
    const float* ob    = (const float*)d_in[11];
    const float* a_q   = (const float*)d_in[12];
    const float* a_k   = (const float*)d_in[13];
    const float* a_v   = (const float*)d_in[14];
    const float* a_o   = (const float*)d_in[15];
    const float* val_W = (const float*)d_in[16];
    const float* val_b = (const float*)d_in[17];
    const float* a_val = (const float*)d_in[18];
    const float* off_W = (const float*)d_in[19];
    const float* off_b = (const float*)d_in[20];
    const float* aw_W  = (const float*)d_in[21];
    const float* aw_b  = (const float*)d_in[22];
    const float* out_W = (const float*)d_in[23];
    const float* out_b = (const float*)d_in[24];
    const float* a_out = (const float*)d_in[25];
    const float* W1    = (const float*)d_in[26];
    const float* b1    = (const float*)d_in[27];
    const float* a_w1  = (const float*)d_in[28];
    const float* W2    = (const float*)d_in[29];
    const float* b2    = (const float*)d_in[30];
    const float* a_w2  = (const float*)d_in[31];
    const float* ln1_g = (const float*)d_in[32];
    const float* ln1_b = (const float*)d_in[33];
    const float* ln2_g = (const float*)d_in[34];
    const float* ln2_b = (const float*)d_in[35];
    const float* ln3_g = (const float*)d_in[36];
    const float* ln3_b = (const float*)d_in[37];

    // ---- workspace layout ----
    u16* wq_q  = (u16*)d_ws;
    u16* wq_k  = wq_q + 65536;
    u16* wq_v  = wq_k + 65536;
    u16* wq_o  = wq_v + 65536;
    u16* wq_vl = wq_o + 65536;
    u16* wq_ot = wq_vl + 65536;
    u16* w_off = wq_ot + 65536;
    u16* w_aw  = w_off + 65536;
    u16* wq_1  = w_aw + 32768;
    u16* wq_2  = wq_1 + 262144;
    u16* bufA  = wq_2 + 262144;      // NELEM bf16 each
    u16* bufB  = bufA + NELEM_;
    u16* bufC  = bufB + NELEM_;
    u16* bufD  = bufC + NELEM_;
    u16* bufE  = bufD + NELEM_;
    float* offs = (float*)(bufE + NELEM_);   // NELEM f32
    float* awb  = offs + NELEM_;             // MQ*128 f32
    u16* valb   = (u16*)(awb + MQ_ * 128);   // B*LIN*256 bf16 (later reused as ffn1)

    const int TB = 256;
    const int MVAL = B_ * LIN_;
    const int GM = MQ_ / 64;                 // 225 (exact)
    const int GV = CDIV(MVAL, 64);           // 2494

    // weights
    k_quant<<<CDIV(65536, TB), TB, 0, stream>>>(qW, a_q, wq_q, 65536);
    k_quant<<<CDIV(65536, TB), TB, 0, stream>>>(kW, a_k, wq_k, 65536);
    k_quant<<<CDIV(65536, TB), TB, 0, stream>>>(vW, a_v, wq_v, 65536);
    k_quant<<<CDIV(65536, TB), TB, 0, stream>>>(oW, a_o, wq_o, 65536);
    k_quant<<<CDIV(65536, TB), TB, 0, stream>>>(val_W, a_val, wq_vl, 65536);
    k_quant<<<CDIV(65536, TB), TB, 0, stream>>>(out_W, a_out, wq_ot, 65536);
    k_quant<<<CDIV(262144, TB), TB, 0, stream>>>(W1, a_w1, wq_1, 262144);
    k_quant<<<CDIV(262144, TB), TB, 0, stream>>>(W2, a_w2, wq_2, 262144);
    k_cvt<<<CDIV(65536, TB), TB, 0, stream>>>(off_W, w_off, 65536);
    k_cvt<<<CDIV(32768, TB), TB, 0, stream>>>(aw_W, w_aw, 32768);

    // activation prep
    k_addcvt<<<CDIV(NELEM_, TB), TB, 0, stream>>>(tgt, qpos, bufA, NELEM_);  // qk_in
    k_cvt<<<CDIV(NELEM_, TB), TB, 0, stream>>>(tgt, bufB, NELEM_);           // tgt_bf

    // ---- self-attention ----
    k_gemm3<u16, u16, false, 128><<<dim3(GM, 2), TB, 0, stream>>>(bufA, wq_q, qb, bufC, MQ_, 256, 256);
    k_gemm3<u16, u16, false, 128><<<dim3(GM, 2), TB, 0, stream>>>(bufA, wq_k, kb, bufD, MQ_, 256, 256);
    k_gemm3<u16, u16, false, 128><<<dim3(GM, 2), TB, 0, stream>>>(bufB, wq_v, vb, bufE, MQ_, 256, 256);
    k_attn<<<dim3(CDIV(LQ_,64), H_, B_), TB, 0, stream>>>(bufC, bufD, bufE, bufA);       // sa -> A
    k_gemm3<u16, u16, false, 128><<<dim3(GM, 2), TB, 0, stream>>>(bufA, wq_o, ob, bufB, MQ_, 256, 256);
    k_resln<float, u16><<<MQ_, TB, 0, stream>>>(bufB, tgt, ln2_g, ln2_b, bufC);          // tgt2 -> C

    // ---- deformable cross-attention ----
    k_addcvt2<<<CDIV(NELEM_, TB), TB, 0, stream>>>(bufC, qpos, bufD, NELEM_);            // query -> D
    k_gemm3<float, u16, false, 256><<<dim3(GV, 1), TB, 0, stream>>>(src, wq_vl, val_b, valb, MVAL, 256, 256);
    k_gemm3<u16, float, false, 128><<<dim3(GM, 2), TB, 0, stream>>>(bufD, w_off, off_b, offs, MQ_, 256, 256);
    k_gemm<u16, float, false><<<dim3(CDIV(MQ_,128), 1), TB, 0, stream>>>(bufD, w_aw, aw_b, awb, MQ_, 128, 256);
    k_sample<<<MQ_ / 2, TB, 0, stream>>>(offs, awb, valb, refp, bufE);                   // acc -> E
    k_gemm3<u16, u16, false, 128><<<dim3(GM, 2), TB, 0, stream>>>(bufE, wq_ot, out_b, bufA, MQ_, 256, 256);
    k_resln<u16, u16><<<MQ_, TB, 0, stream>>>(bufA, bufC, ln1_g, ln1_b, bufB);           // tgt3 -> B

    // ---- FFN ----
    u16* ffn1 = valb;  // value dead after k_sample
    k_gemm3<u16, u16, true , 128><<<dim3(GM, 8), TB, 0, stream>>>(bufB, wq_1, b1, ffn1, MQ_, 1024, 256);
    k_gemm3<u16, u16, false, 128><<<dim3(GM, 2), TB, 0, stream>>>(ffn1, wq_2, b2, bufD, MQ_, 256, 1024);
    k_resln<u16, float><<<MQ_, TB, 0, stream>>>(bufD, bufB, ln3_g, ln3_b, (float*)d_out);
}